// Round 3
// baseline (3231.853 us; speedup 1.0000x reference)
//
#include <hip/hip_runtime.h>
#include <hip/hip_bf16.h>
#include <math.h>

typedef short s8v __attribute__((ext_vector_type(8)));
typedef float f4v __attribute__((ext_vector_type(4)));
typedef float f8v __attribute__((ext_vector_type(8)));

#define D_    768
#define M_    5
#define DS_   768
#define NH_   12
#define B_    8
#define V_    512
#define S_    128
#define T_    16
#define A_    8
#define DIN_  6144
#define NP    (1 << 30)

// split fp32 x into bf16 hi (truncate) + bf16 lo (truncate of exact residual)
__device__ __forceinline__ void split8(const f8v& x, s8v& hi, s8v& lo) {
#pragma unroll
    for (int j = 0; j < 8; j++) {
        unsigned xu = __float_as_uint(x[j]);
        float hf = __uint_as_float(xu & 0xFFFF0000u);
        float r  = x[j] - hf;                       // exact in fp32
        hi[j] = (short)(xu >> 16);
        lo[j] = (short)(__float_as_uint(r) >> 16);
    }
}

__device__ __forceinline__ void split1(float v, short& h, short& l) {
    unsigned xu = __float_as_uint(v);
    float hf = __uint_as_float(xu & 0xFFFF0000u);
    h = (short)(xu >> 16);
    l = (short)(__float_as_uint(v - hf) >> 16);
}

// elementwise fp32 -> (hi,lo) bf16 pair conversion; n8 = n/8 vectors
__global__ void split_arr(const float* __restrict__ x, short* __restrict__ hi,
                          short* __restrict__ lo, long n8)
{
    long i = (long)blockIdx.x * 256 + threadIdx.x;
    if (i >= n8) return;
    f8v v = *(const f8v*)(x + i * 8);
    s8v h, l;
    split8(v, h, l);
    *(s8v*)(hi + i * 8) = h;
    *(s8v*)(lo + i * 8) = l;
}

// ===== split-bf16 MFMA GEMM, pre-split operands: C = act(scale*(A @ W^T) + bias [+res]) =====
// A row r (within z-slice): off = ab + aoff + (r/arpb)*abst + (r%arpb)*lda (+ frag k offset).
// 3-level z-batch: zh_all=z/zdiv, zl=z%zdiv, zt=zh_all/zdiv2, zh=zh_all%zdiv2:
//   ab = zt*az1b + zh*az1 + zl*az2 (same for W with wz*, out with oz*).
// Out: ob + (row/orpb)*ostride + (row%orpb)*osub + coff + col*cscale.
// OMODE: 0 = fp32 only, 1 = split(hi,lo) only, 2 = both.
// WSPLIT=false: W read fp32 from Wf and split on the fly (pre_w1 fallback).
// 256 thr = 4 waves; tile 64(M) x 128(N); wave w covers cols [w*32, w*32+32).
template<int ACT, bool RES, int OMODE, bool WSPLIT>
__global__ __launch_bounds__(256)
void mm(const short* __restrict__ Ahi, const short* __restrict__ Alo,
        int lda, int arpb, long abst, long aoff,
        long az1b, long az1, long az2, int zdiv2, int zdiv,
        const short* __restrict__ Whi, const short* __restrict__ Wlo,
        const float* __restrict__ Wf,
        long woff, int ldw, long wz1b, long wz1, long wz2,
        const float* __restrict__ bias, long boff, float scale,
        float* __restrict__ Cout, short* __restrict__ Ohi, short* __restrict__ Olo,
        long oz1b, long oz1, long oz2,
        int orpb, long ostride, long osub, long coff, long cscale,
        const float* __restrict__ res,
        int M, int N, int K)
{
    const int tid = threadIdx.x;
    const int w = tid >> 6, l = tid & 63, q = l >> 4, ln = l & 15;
    const int n0 = blockIdx.x * 128 + w * 32;
    const int m0 = blockIdx.y * 64;
    const int z = blockIdx.z;
    int zh_all = z / zdiv, zl = z - zh_all * zdiv;
    int zt = zh_all / zdiv2, zh = zh_all - zt * zdiv2;
    long ab = (long)zt * az1b + (long)zh * az1 + (long)zl * az2;
    long wb = (long)zt * wz1b + (long)zh * wz1 + (long)zl * wz2;
    long ob = (long)zt * oz1b + (long)zh * oz1 + (long)zl * oz2;

    long aofs[4];
#pragma unroll
    for (int mf = 0; mf < 4; mf++) {
        int rm = m0 + mf * 16 + ln;
        if (rm > M - 1) rm = M - 1;
        aofs[mf] = ab + aoff + (long)(rm / arpb) * abst + (long)(rm % arpb) * lda + q * 8;
    }
    long wofs[2];
#pragma unroll
    for (int nf = 0; nf < 2; nf++)
        wofs[nf] = woff + wb + (long)(n0 + nf * 16 + ln) * ldw + q * 8;

    f4v acc[4][2];
#pragma unroll
    for (int mf = 0; mf < 4; mf++)
#pragma unroll
        for (int nf = 0; nf < 2; nf++)
#pragma unroll
            for (int r = 0; r < 4; r++) acc[mf][nf][r] = 0.f;

#pragma unroll 2
    for (int k = 0; k < K; k += 32) {
        s8v ah[4], al[4], bh[2], bl[2];
#pragma unroll
        for (int mf = 0; mf < 4; mf++) {
            ah[mf] = *(const s8v*)(const void*)(Ahi + aofs[mf] + k);
            al[mf] = *(const s8v*)(const void*)(Alo + aofs[mf] + k);
        }
#pragma unroll
        for (int nf = 0; nf < 2; nf++) {
            if (WSPLIT) {
                bh[nf] = *(const s8v*)(const void*)(Whi + wofs[nf] + k);
                bl[nf] = *(const s8v*)(const void*)(Wlo + wofs[nf] + k);
            } else {
                f8v wv = *(const f8v*)(const void*)(Wf + wofs[nf] + k);
                split8(wv, bh[nf], bl[nf]);
            }
        }
#pragma unroll
        for (int mf = 0; mf < 4; mf++)
#pragma unroll
            for (int nf = 0; nf < 2; nf++) {
                acc[mf][nf] = __builtin_amdgcn_mfma_f32_16x16x32_bf16(ah[mf], bh[nf], acc[mf][nf], 0, 0, 0);
                acc[mf][nf] = __builtin_amdgcn_mfma_f32_16x16x32_bf16(ah[mf], bl[nf], acc[mf][nf], 0, 0, 0);
                acc[mf][nf] = __builtin_amdgcn_mfma_f32_16x16x32_bf16(al[mf], bh[nf], acc[mf][nf], 0, 0, 0);
            }
    }

#pragma unroll
    for (int mf = 0; mf < 4; mf++) {
#pragma unroll
        for (int r = 0; r < 4; r++) {
            int row = m0 + mf * 16 + q * 4 + r;
            if (row >= M) continue;
#pragma unroll
            for (int nf = 0; nf < 2; nf++) {
                int col = n0 + nf * 16 + ln;
                if (col >= N) continue;
                float v = acc[mf][nf][r];
                v *= scale;
                if (bias) v += bias[boff + col];
                if (ACT) v = fmaxf(v, 0.f);
                if (RES) v += res[(size_t)(row >> 3) * 768 + col];
                long o = ob + (long)(row / orpb) * ostride + (long)(row % orpb) * osub
                       + coff + (long)col * cscale;
                if (OMODE == 0 || OMODE == 2) Cout[o] = v;
                if (OMODE >= 1) { short h, lo2; split1(v, h, lo2); Ohi[o] = h; Olo[o] = lo2; }
            }
        }
    }
}

// row-wise in-place softmax; also emits split(hi,lo); grid.x = #rows, 256 threads
__global__ void softmax_rows(float* __restrict__ sc, short* __restrict__ hi,
                             short* __restrict__ lo, int len)
{
    size_t base = (size_t)blockIdx.x * len;
    float* p = sc + base;
    __shared__ float red[256];
    int tid = threadIdx.x;
    float m = -1e30f;
    for (int i = tid; i < len; i += 256) m = fmaxf(m, p[i]);
    red[tid] = m; __syncthreads();
    for (int o = 128; o > 0; o >>= 1) {
        if (tid < o) red[tid] = fmaxf(red[tid], red[tid + o]);
        __syncthreads();
    }
    float mx = red[0]; __syncthreads();
    float s = 0.f;
    for (int i = tid; i < len; i += 256) { float e = expf(p[i] - mx); p[i] = e; s += e; }
    red[tid] = s; __syncthreads();
    for (int o = 128; o > 0; o >>= 1) {
        if (tid < o) red[tid] += red[tid + o];
        __syncthreads();
    }
    float inv = 1.f / red[0]; __syncthreads();
    for (int i = tid; i < len; i += 256) {
        float v = p[i] * inv;
        p[i] = v;
        short h, l2; split1(v, h, l2);
        hi[base + i] = h; lo[base + i] = l2;
    }
}

// wmask over chunk: block z = tch*8 + b; sc2 laid [tch][b][h][8][128]; split output
__global__ void wmask_kernel(const float* __restrict__ sc2, short* __restrict__ wh,
                             short* __restrict__ wl)
{
    int z = blockIdx.x;
    const float* src = sc2 + (size_t)z * 12288;
    for (int idx = threadIdx.x; idx < 1024; idx += 256) {
        float s = 0.f;
        for (int h = 0; h < NH_; h++) s += src[h * 1024 + idx];
        float v = s * (1.f / 12.f);
        short h2, l2; split1(v, h2, l2);
        wh[(size_t)z * 1024 + idx] = h2;
        wl[(size_t)z * 1024 + idx] = l2;
    }
}

// GRU states for all 8 candidate predecessors of every (t, b, a); split output.
// chunk rows: R = tloc*512 + b*64 + ap*8 + a
__global__ void gru_cand(const float* __restrict__ gi_all, const float* __restrict__ ghall,
                         const float* __restrict__ gh0, const float* __restrict__ pre_all,
                         const float* __restrict__ s0p,
                         short* __restrict__ sh, short* __restrict__ sl, int t0c)
{
    long idx = (long)blockIdx.x * 256 + threadIdx.x;   // exactly nt*512*768
    int c = (int)(idx % 768);
    long r = idx / 768;
    int tloc = (int)(r / 512), rem = (int)(r % 512);
    int b = rem >> 6, ap = (rem >> 3) & 7, a = rem & 7;
    int t = t0c + tloc;
    const float* gi = gi_all + ((long)t * 64 + b * 8 + a) * 2304;
    const float* gh; float hv;
    if (t == 0) { gh = gh0; hv = s0p[c]; }
    else {
        long j = (long)(t - 1) * 64 + b * 8 + ap;
        gh = ghall + j * 2304;
        hv = pre_all[j * 768 + c];
    }
    float ir  = gi[c], iz = gi[768 + c], inn = gi[1536 + c];
    float rg = 1.f / (1.f + expf(-(ir + gh[c])));
    float zg = 1.f / (1.f + expf(-(iz + gh[768 + c])));
    float ng = tanhf(inn + rg * gh[1536 + c]);
    float v = (1.f - zg) * ng + zg * hv;
    short h2, l2; split1(v, h2, l2);
    sh[idx] = h2; sl[idx] = l2;
}

// logits for candidate rows: lc[t0c*512 + blk*64 + r] = s1H_row . w2 + b2
__global__ void logits_cand_k(const float* __restrict__ s1H, const float* __restrict__ w2,
                              const float* __restrict__ b2, float* __restrict__ lc, int t0c)
{
    __shared__ float red[256];
    int blk = blockIdx.x;
    int tid = threadIdx.x, r = tid >> 2, p = tid & 3;
    const float* rp = s1H + ((size_t)blk * 64 + r) * 768 + p * 192;
    const float* wp = w2 + p * 192;
    float s = 0.f;
    for (int i = 0; i < 192; i++) s = fmaf(rp[i], wp[i], s);
    red[tid] = s; __syncthreads();
    if (p == 0)
        lc[(size_t)t0c * 512 + (size_t)blk * 64 + r]
            = red[tid] + red[tid + 1] + red[tid + 2] + red[tid + 3] + b2[0];
}

// walk the argmax chain through the precomputed candidate-logits table; 64 threads
__global__ void chain_k(const float* __restrict__ lc, float* __restrict__ out)
{
    __shared__ float lrow[64];
    __shared__ int am[8];
    int tid = threadIdx.x;            // b*8 + a
    int b = tid >> 3, a = tid & 7;
    for (int t = 0; t < T_; t++) {
        int cand = (t == 0) ? 0 : am[b];
        float v = lc[t * 512 + b * 64 + cand * 8 + a];
        out[((size_t)(b * T_ + t)) * A_ + a] = v;
        lrow[tid] = v;
        __syncthreads();
        if (a == 0) {
            float best = lrow[b * 8]; int bi = 0;
            for (int x = 1; x < 8; x++) { float w = lrow[b * 8 + x]; if (w > best) { best = w; bi = x; } }
            am[b] = bi;
        }
        __syncthreads();
    }
}

// ===== host =====
struct SB { short* h; short* l; };

template<int ACT, int OM>
static inline void MMs(hipStream_t st, SB A, int lda, int arpb, long abst, long aoff,
                       SB W, long woff, int ldw, const float* bias, long boff,
                       float* Cf, SB O, long ldc, long coff, int M, int N, int K)
{
    dim3 g((unsigned)((N + 127) / 128), (unsigned)((M + 63) / 64), 1), b(256);
    mm<ACT, false, OM, true><<<g, b, 0, st>>>(A.h, A.l, lda, arpb, abst, aoff,
        0, 0, 0, NP, 1, W.h, W.l, nullptr, woff, ldw, 0, 0, 0,
        bias, boff, 1.f, Cf, O.h, O.l, 0, 0, 0, 1, ldc, 0, coff, 1, nullptr, M, N, K);
}

extern "C" void kernel_launch(void* const* d_in, const int* in_sizes, int n_in,
                              void* d_out, int out_size, void* d_ws, size_t ws_size,
                              hipStream_t stream)
{
    const float* video     = (const float*)d_in[0];
    const float* script    = (const float*)d_in[1];
    const float* question  = (const float*)d_in[2];
    const float* a_texts   = (const float*)d_in[3];
    const float* a_buttons = (const float*)d_in[4];
    const float* state0    = (const float*)d_in[5];
    const float* mlp_v_w1 = (const float*)d_in[6];  const float* mlp_v_b1 = (const float*)d_in[7];
    const float* mlp_v_w2 = (const float*)d_in[8];  const float* mlp_v_b2 = (const float*)d_in[9];
    const float* mlp_t_w1 = (const float*)d_in[10]; const float* mlp_t_b1 = (const float*)d_in[11];
    const float* mlp_t_w2 = (const float*)d_in[12]; const float* mlp_t_b2 = (const float*)d_in[13];
    const float* pre_w1   = (const float*)d_in[14]; const float* pre_b1   = (const float*)d_in[15];
    const float* pre_w2   = (const float*)d_in[16]; const float* pre_b2   = (const float*)d_in[17];
    const float* s2v_in_w = (const float*)d_in[18]; const float* s2v_in_b = (const float*)d_in[19];
    const float* s2v_out_w= (const float*)d_in[20]; const float* s2v_out_b= (const float*)d_in[21];
    const float* qa2s_in_w= (const float*)d_in[22]; const float* qa2s_in_b= (const float*)d_in[23];
    const float* qa2s_out_w=(const float*)d_in[24]; const float* qa2s_out_b=(const float*)d_in[25];
    const float* gru_w_ih = (const float*)d_in[26]; const float* gru_w_hh = (const float*)d_in[27];
    const float* gru_b_ih = (const float*)d_in[28]; const float* gru_b_hh = (const float*)d_in[29];
    const float* proj_w1  = (const float*)d_in[30]; const float* proj_b1  = (const float*)d_in[31];
    const float* proj_w2  = (const float*)d_in[32]; const float* proj_b2  = (const float*)d_in[33];
    float* out = (float*)d_out;
    (void)in_sizes; (void)n_in; (void)out_size;

    hipStream_t st = stream;
    dim3 blk(256);
    const long DDL = 589824;

    // ---- workspace bump allocator (units of 4 bytes) ----
    float* fb = (float*)d_ws;
    auto take = [&](long n) { float* p = fb; fb += n; return p; };
    auto mksb = [&](long n) { float* p = take(n); SB s; s.h = (short*)p; s.l = s.h + n; return s; };

    // split weights (persistent)
    SB w_v1 = mksb(589824),  w_v2 = mksb(589824);
    SB w_t1 = mksb(589824),  w_t2 = mksb(589824);
    SB s2vi = mksb(1769472), s2vo = mksb(589824);
    SB qa2i = mksb(1769472), qa2o = mksb(589824);
    SB gih  = mksb(1769472), ghh  = mksb(1769472);
    SB pj1  = mksb(589824),  pw2  = mksb(4718592);
    // split inputs
    SB sVid = mksb(3145728), sScr = mksb(786432), sQue = mksb(6144);
    SB sAtx = mksb(786432),  sAbt = mksb(3932160), sS0 = mksb(768);
    // persistent activations
    SB svat = mksb(786432), sk2 = mksb(786432), sv2T = mksb(786432);
    float* q_t     = take(6144);
    float* gh0     = take(2304);
    float* pre_all = take(786432);
    SB spre        = mksb(786432);
    float* lc      = take(8192);

    long wsF = (long)(ws_size / 4);
    long dynMin = 5505024;
    bool w1split = ((fb - (float*)d_ws) + 37748736L + dynMin + 64) <= wsF;
    SB pw1s = { nullptr, nullptr };
    if (w1split) pw1s = mksb(37748736);

    float* U = fb;
    long dynF = wsF - (fb - (float*)d_ws) - 64;

    int g = 1;
    for (int c = 8; c >= 1; c >>= 1) { if (1572864L + (long)c * 2752512L <= dynF) { g = c; break; } }
    int TG = 1;
    for (int c = 16; c >= 1; c >>= 1) { if ((long)c * 1384448L <= dynF) { TG = c; break; } }
    int TG2 = 1;
    for (int c = 16; c >= 1; c >>= 1) { if (4718592L + (long)c * 786432L <= dynF) { TG2 = c; break; } }

    // ---- conversions ----
    auto SPL = [&](const float* x, SB s, long n) {
        long n8 = n / 8;
        split_arr<<<dim3((unsigned)((n8 + 255) / 256)), blk, 0, st>>>(x, s.h, s.l, n8);
    };
    SPL(mlp_v_w1, w_v1, 589824);  SPL(mlp_v_w2, w_v2, 589824);
    SPL(mlp_t_w1, w_t1, 589824);  SPL(mlp_t_w2, w_t2, 589824);
    SPL(s2v_in_w, s2vi, 1769472); SPL(s2v_out_w, s2vo, 589824);
    SPL(qa2s_in_w, qa2i, 1769472);SPL(qa2s_out_w, qa2o, 589824);
    SPL(gru_w_ih, gih, 1769472);  SPL(gru_w_hh, ghh, 1769472);
    SPL(proj_w1, pj1, 589824);    SPL(pre_w2, pw2, 4718592);
    SPL(video, sVid, 3145728);    SPL(script, sScr, 786432);
    SPL(question, sQue, 6144);    SPL(a_texts, sAtx, 786432);
    SPL(a_buttons, sAbt, 3932160);SPL(state0, sS0, 768);
    if (w1split) SPL(pre_w1, pw1s, 37748736);

    // ======== phase 1 ========
    // phase-1 view of U
    SB sqp   = { (short*)U, (short*)U + 786432 };
    SB satt  = { (short*)(U + 786432), (short*)(U + 786432) + 786432 };
    float* G0 = U + 1572864;
    SB sbufA = { (short*)G0, (short*)G0 + (long)g * 393216 };
    SB sbufB = { (short*)(G0 + (long)g * 393216), (short*)(G0 + (long)g * 393216) + (long)g * 393216 };
    SB sbufD = { (short*)(G0 + 2L * g * 393216), (short*)(G0 + 2L * g * 393216) + (long)g * 393216 };
    float* sc_g = G0 + 3L * g * 393216;
    SB ssc_g = { (short*)(sc_g + (long)g * 786432), (short*)(sc_g + (long)g * 786432) + (long)g * 786432 };
    SB sscrH = { (short*)G0, (short*)G0 + 786432 };
    SB sscrT = { (short*)(G0 + 786432), (short*)(G0 + 786432) + 786432 };
    SB sqH   = { (short*)(G0 + 1572864), (short*)(G0 + 1572864) + 6144 };

    MMs<0, 1>(st, sScr, D_, NP, 0, 0, s2vi, 0, D_, s2v_in_b, 0, nullptr, sqp, D_, 0, 1024, D_, D_);
    for (int s0 = 0; s0 < B_; s0 += g) {
        int Mg = 512 * g;
        long voff = (long)s0 * 393216;
        MMs<1, 1>(st, sVid, D_, NP, 0, voff, w_v1, 0, D_, mlp_v_b1, 0, nullptr, sbufA, D_, 0, Mg, D_, D_);
        MMs<0, 1>(st, sbufA, D_, NP, 0, 0, w_v2, 0, D_, mlp_v_b2, 0, nullptr, sbufB, D_, 0, Mg, D_, D_);
        MMs<0, 1>(st, sbufB, D_, NP, 0, 0, s2vi, DDL, D_, s2v_in_b, D_, nullptr, sbufA, D_, 0, Mg, D_, D_); // kp
        {   // vpT: out o = (row/512)*393216 + row%512 + col*512
            dim3 gr(6, (unsigned)(Mg / 64), 1);
            mm<0, false, 1, true><<<gr, blk, 0, st>>>(sbufB.h, sbufB.l, D_, NP, 0, 0, 0, 0, 0, NP, 1,
                s2vi.h, s2vi.l, nullptr, 2 * DDL, D_, 0, 0, 0, s2v_in_b, 2 * D_, 1.f,
                nullptr, sbufD.h, sbufD.l, 0, 0, 0, 512, 393216, 1, 0, 512, nullptr, Mg, D_, D_);
        }
        {   // scores (fp32): sc_g[z=lb*12+h][i][j] = 0.125 * qp_i . kp_j (dh slice h)
            dim3 gr(4, 2, (unsigned)(12 * g));
            mm<0, false, 0, true><<<gr, blk, 0, st>>>(sqp.h, sqp.l, D_, NP, 0, (long)s0 * 98304,
                0, 98304, 64, NP, 12,
                sbufA.h, sbufA.l, nullptr, 0, D_, 0, 393216, 64, nullptr, 0, 0.125f,
                sc_g, nullptr, nullptr, 0, 786432, 65536, 1, 512, 0, 0, 1, nullptr, S_, V_, 64);
        }
        softmax_rows<<<dim3((unsigned)(12 * g * 128)), blk, 0, st>>>(sc_g, ssc_g.h, ssc_g.l, 512);
        {   // PV: attnout[b*128+i][h*64+d] = P . V
            dim3 gr(1, 2, (unsigned)(12 * g));
            mm<0, false, 1, true><<<gr, blk, 0, st>>>(ssc_g.h, ssc_g.l, 512, NP, 0, 0,
                0, 786432, 65536, NP, 12,
                sbufD.h, sbufD.l, nullptr, 0, 512, 0, 393216, 32768, nullptr, 0, 1.f,
                nullptr, satt.h, satt.l, 0, 98304, 64, 1, 768, 0, (long)s0 * 98304, 1, nullptr, S_, 64, 512);
        }
    }
    {   // vid_attT: out o = (row/128)*98304 + row%128 + col*128
        dim3 gr(6, 16, 1);
        mm<0, false, 1, true><<<gr, blk, 0, st>>>(satt.h, satt.l, D_, NP, 0, 0, 0, 0, 0, NP, 1,
            s2vo.h, s2vo.l, nullptr, 0, D_, 0, 0, 0, s2v_out_b, 0, 1.f,
            nullptr, svat.h, svat.l, 0, 0, 0, 128, 98304, 1, 0, 128, nullptr, 1024, D_, D_);
    }
    MMs<1, 1>(st, sScr, D_, NP, 0, 0, w_t1, 0, D_, mlp_t_b1, 0, nullptr, sscrH, D_, 0, 1024, D_, D_);
    MMs<0, 1>(st, sscrH, D_, NP, 0, 0, w_t2, 0, D_, mlp_t_b2, 0, nullptr, sscrT, D_, 0, 1024, D_, D_);
    MMs<0, 1>(st, sscrT, D_, NP, 0, 0, qa2i, DDL, D_, qa2s_in_b, D_, nullptr, sk2, D_, 0, 1024, D_, D_);
    {   // v2T: out o = (row/128)*98304 + row%128 + col*128
        dim3 gr(6, 16, 1);
        mm<0, false, 1, true><<<gr, blk, 0, st>>>(sscrT.h, sscrT.l, D_, NP, 0, 0, 0, 0, 0, NP, 1,
            qa2i.h, qa2i.l, nullptr, 2 * DDL, D_, 0, 0, 0, qa2s_in_b, 2 * D_, 1.f,
            nullptr, sv2T.h, sv2T.l, 0, 0, 0, 128, 98304, 1, 0, 128, nullptr, 1024, D_, D_);
    }
    MMs<1, 1>(st, sQue, D_, NP, 0, 0, w_t1, 0, D_, mlp_t_b1, 0, nullptr, sqH, D_, 0, B_, D_, D_);
    MMs<0, 0>(st, sqH, D_, NP, 0, 0, w_t2, 0, D_, mlp_t_b2, 0, q_t, SB{nullptr, nullptr}, D_, 0, B_, D_, D_);

    // ======== batched scan precompute (chunks of TG timesteps) ========
    for (int t0 = 0; t0 < T_; t0 += TG) {
        float* p = U;
        SB sinp  = { (short*)p, (short*)p + (long)TG * 393216 }; p += (long)TG * 393216;
        SB spreH = { (short*)p, (short*)p + (long)TG * 393216 }; p += (long)TG * 393216;
        SB satH  = { (short*)p, (short*)p + (long)TG * 49152 };  p += (long)TG * 49152;
        SB sabH  = { (short*)p, (short*)p + (long)TG * 245760 }; p += (long)TG * 245760;
        SB sqp2  = { (short*)p, (short*)p + (long)TG * 49152 };  p += (long)TG * 49152;
        float* sc2 = p;                                          p += (long)TG * 98304;
        SB ssc2  = { (short*)p, (short*)p + (long)TG * 98304 };  p += (long)TG * 98304;
        SB swm   = { (short*)p, (short*)p + (long)TG * 8192 };   p += (long)TG * 8192;
        SB satt2 = { (short*)p, (short*)p + (long)TG * 49152 };  p += (long)TG * 49152;

        // a_t layer1 (gather over t), z = tch
        mm<1, false, 1, true><<<dim3(6, 1, TG), blk, 0, st>>>(sAtx.h, sAtx.l, D_, A_, 98304,
            (long)t0 * 6144, 0, 6144, 0, NP, 1,
            w_t1.h, w_t1.l, nullptr, 0, D_, 0, 0, 0, mlp_t_b1, 0, 1.f,
            nullptr, satH.h, satH.l, 0, 49152, 0, 1, 768, 0, 0, 1, nullptr, 64, D_, D_);
        // a_t layer2 + q_t -> inputs[:,1536:2304]
        mm<0, true, 1, true><<<dim3(6, 1, TG), blk, 0, st>>>(satH.h, satH.l, D_, NP, 0, 0,
            0, 49152, 0, NP, 1,
            w_t2.h, w_t2.l, nullptr, 0, D_, 0, 0, 0, mlp_t_b2, 0, 1.f,
            nullptr, sinp.h, sinp.l, 0, 393216, 0, 1, DIN_, 0, 1536, 1, q_t, 64, D_, D_);
        // a_b layer1 (gather over t)
        mm<1, false, 1, true><<<dim3(6, 5, TG), blk, 0, st>>>(sAbt.h, sAbt.l, D_, A_ * M_, 491520,
            (long)t0 * 30720, 0, 30720, 0, NP, 1,
            w_v1.h, w_v1.l, nullptr, 0, D_, 0, 0, 0, mlp_v_b1, 0, 1.f,
            nullptr, sabH.h, sabH.l, 0, 245760, 0, 1, 768, 0, 0, 1, nullptr, 320, D_, D_);
        // a_b layer2 -> inputs[:,2304:6144]
        mm<0, false, 1, true><<<dim3(6, 5, TG), blk, 0, st>>>(sabH.h, sabH.l, D_, NP, 0, 0,
            0, 245760, 0, NP, 1,
            w_v2.h, w_v2.l, nullptr, 0, D_, 0, 0, 0, mlp_v_b2, 0, 1.f,
            nullptr, sinp.h, sinp.l, 0, 393216, 0, M_, DIN_, 768, 2304, 1, nullptr, 320, D_, D_);
        // qp2 = qa @ qa2s_wq
        mm<0, false, 1, true><<<dim3(6, 1, TG), blk, 0, st>>>(sinp.h, sinp.l, DIN_, NP, 0, 1536,
            0, 393216, 0, NP, 1,
            qa2i.h, qa2i.l, nullptr, 0, D_, 0, 0, 0, qa2s_in_b, 0, 1.f,
            nullptr, sqp2.h, sqp2.l, 0, 49152, 0, 1, 768, 0, 0, 1, nullptr, 64, D_, D_);
        // scores2 (fp32): z = tch*96 + b*12 + h
        mm<0, false, 0, true><<<dim3(1, 1, 96 * TG), blk, 0, st>>>(sqp2.h, sqp2.l, D_, NP, 0, 0,
            49152, 6144, 64, 8, 12,
            sk2.h, sk2.l, nullptr, 0, D_, 0, 98304, 64, nullptr, 0, 0.125f,
            sc2, nullptr, nullptr, 98304, 12288, 1024, 1, 128, 0, 0, 1, nullptr, A_, S_, 64);
        softmax_rows<<<dim3((unsigned)(768 * TG)), blk, 0, st>>>(sc2, ssc2.h, ssc2.l, 128);
        wmask_kernel<<<dim3((unsigned)(8 * TG)), blk, 0, st>>>(sc2, swm.h, swm.l);
        // qa_vid = wmask @ vid_att -> inputs[:,0:768]; z = tch*8 + b
        mm<0, false, 1, true><<<dim3(6, 1, 8 * TG), blk, 0, st>>>(swm.h, swm.l, S_, NP, 0, 0,
            0, 8192, 1024, NP, 8,
            svat.h, svat.l, nullptr, 0, 128, 0, 0, 98304, nullptr, 0, 1.f,
            nullptr, sinp.h, sinp.l, 0, 393216, 49152, 1, DIN_, 0, 0, 1, nullptr, A_, D_, S_);
        // PV2 -> att2; z = tch*96 + b*12 + h
        mm<0, false, 1, true><<<dim3(1, 1, 96 * TG), blk, 0, st>>>(ssc2.h, ssc2.l, S_, NP, 0, 0,
            98304, 12288, 1024, 8, 12,
            sv2T.h, sv2T.l, nullptr, 0, 128, 0, 98304, 8192, nullptr, 0, 1.f,
            nullptr, satt2.h, satt2.l, 49152, 6144, 64, 1, 768, 0, 0, 1, nullptr, A_, 64, S_);
        // attn out-proj -> inputs[:,768:1536]
        mm<0, false, 1, true><<<dim3(6, 1, TG), blk, 0, st>>>(satt2.h, satt2.l, D_, NP, 0, 0,
            0, 49152, 0, NP, 1,
            qa2o.h, qa2o.l, nullptr, 0, D_, 0, 0, 0, qa2s_out_b, 0, 1.f,
            nullptr, sinp.h, sinp.l, 0, 393216, 0, 1, DIN_, 0, 768, 1, nullptr, 64, D_, D_);
        // pre-MLP L1 (the big batched GEMM): M = TG*64
        if (w1split)
            mm<1, false, 1, true><<<dim3(48, TG, 1), blk, 0, st>>>(sinp.h, sinp.l, DIN_, NP, 0, 0,
                0, 0, 0, NP, 1,
                pw1s.h, pw1s.l, nullptr, 0, DIN_, 0, 0, 0, pre_b1, 0, 1.f,
                nullptr, spreH.h, spreH.l, 0, 0, 0, 1, DIN_, 0, 0, 1, nullptr, TG * 64, DIN_, DIN_);
        else
            mm<1, false, 1, false><<<dim3(48, TG, 1), blk, 0, st>>>(sinp.h, sinp.l, DIN_, NP, 0, 0,
                0, 0, 0, NP, 1,
                nullptr, nullptr, pre_w1, 0, DIN_, 0, 0, 0, pre_b1, 0, 1.f,
                nullptr, spreH.h, spreH.l, 0, 0, 0, 1, DIN_, 0, 0, 1, nullptr, TG * 64, DIN_, DIN_);
        // pre-MLP L2 -> pre_all (fp32 + split)
        mm<0, false, 2, true><<<dim3(6, TG, 1), blk, 0, st>>>(spreH.h, spreH.l, DIN_, NP, 0, 0,
            0, 0, 0, NP, 1,
            pw2.h, pw2.l, nullptr, 0, DIN_, 0, 0, 0, pre_b2, 0, 1.f,
            pre_all, spre.h, spre.l, 0, 0, 0, 1, 768, 0, (long)t0 * 49152, 1, nullptr, TG * 64, DS_, DIN_);
    }

    // ======== GRU candidate precompute ========
    float* gi_all = U;
    float* ghall  = U + 2359296;
    float* candU  = U + 4718592;
    MMs<0, 0>(st, spre, DS_, NP, 0, 0, gih, 0, DS_, gru_b_ih, 0, gi_all, SB{nullptr, nullptr}, 3 * DS_, 0, 1024, 3 * DS_, DS_);
    MMs<0, 0>(st, spre, DS_, NP, 0, 0, ghh, 0, DS_, gru_b_hh, 0, ghall, SB{nullptr, nullptr}, 3 * DS_, 0, 1024, 3 * DS_, DS_);
    MMs<0, 0>(st, sS0, DS_, NP, 0, 0, ghh, 0, DS_, gru_b_hh, 0, gh0, SB{nullptr, nullptr}, 3 * DS_, 0, 1, 3 * DS_, DS_);

    for (int t0 = 0; t0 < T_; t0 += TG2) {
        float* p = candU;
        SB sstc = { (short*)p, (short*)p + (long)TG2 * 393216 };
        float* s1H = p + (long)TG2 * 393216;
        gru_cand<<<dim3((unsigned)(TG2 * 1536)), blk, 0, st>>>(gi_all, ghall, gh0, pre_all,
                                                               state0, sstc.h, sstc.l, t0);
        MMs<1, 0>(st, sstc, DS_, NP, 0, 0, pj1, 0, DS_, proj_b1, 0, s1H, SB{nullptr, nullptr}, DS_, 0, TG2 * 512, DS_, DS_);
        logits_cand_k<<<dim3((unsigned)(TG2 * 8)), blk, 0, st>>>(s1H, proj_w2, proj_b2, lc, t0);
    }

    // ======== sequential argmax chain (trivial) ========
    chain_k<<<1, 64, 0, st>>>(lc, out);
}

// Round 4
// 1809.954 us; speedup vs baseline: 1.7856x; 1.7856x over previous
//
#include <hip/hip_runtime.h>
#include <hip/hip_bf16.h>
#include <math.h>

typedef short s8v __attribute__((ext_vector_type(8)));
typedef float f4v __attribute__((ext_vector_type(4)));
typedef float f8v __attribute__((ext_vector_type(8)));

#define D_    768
#define M_    5
#define DS_   768
#define NH_   12
#define B_    8
#define V_    512
#define S_    128
#define T_    16
#define A_    8
#define DIN_  6144
#define NP    (1 << 30)

// split fp32 x into bf16 hi (truncate) + bf16 lo (truncate of exact residual)
__device__ __forceinline__ void split8(const f8v& x, s8v& hi, s8v& lo) {
#pragma unroll
    for (int j = 0; j < 8; j++) {
        unsigned xu = __float_as_uint(x[j]);
        float hf = __uint_as_float(xu & 0xFFFF0000u);
        float r  = x[j] - hf;                       // exact in fp32
        hi[j] = (short)(xu >> 16);
        lo[j] = (short)(__float_as_uint(r) >> 16);
    }
}

__device__ __forceinline__ void split1(float v, short& h, short& l) {
    unsigned xu = __float_as_uint(v);
    float hf = __uint_as_float(xu & 0xFFFF0000u);
    h = (short)(xu >> 16);
    l = (short)(__float_as_uint(v - hf) >> 16);
}

// async global->LDS, 16B per lane; LDS dest = wave-uniform base + lane*16
__device__ __forceinline__ void gld16(const short* g, short* l) {
    __builtin_amdgcn_global_load_lds(
        (const __attribute__((address_space(1))) unsigned int*)(g),
        (__attribute__((address_space(3))) unsigned int*)(l), 16, 0, 0);
}

// elementwise fp32 -> (hi,lo) bf16 pair conversion; n8 = n/8 vectors
__global__ void split_arr(const float* __restrict__ x, short* __restrict__ hi,
                          short* __restrict__ lo, long n8)
{
    long i = (long)blockIdx.x * 256 + threadIdx.x;
    if (i >= n8) return;
    f8v v = *(const f8v*)(x + i * 8);
    s8v h, l;
    split8(v, h, l);
    *(s8v*)(hi + i * 8) = h;
    *(s8v*)(lo + i * 8) = l;
}

// ===== LDS-staged split-bf16 MFMA GEMM: C = act(scale*(A @ W^T) + bias [+res]) =====
// Same addressing semantics as before:
// A row r: off = ab + aoff + (r/arpb)*abst + (r%arpb)*lda (+k).
// z: zh_all=z/zdiv, zl=z%zdiv, zt=zh_all/zdiv2, zh=zh_all%zdiv2;
//   ab=zt*az1b+zh*az1+zl*az2 (W: wz*, out: oz*). W row n: woff+wb+n*ldw.
// Out: ob + (row/orpb)*ostride + (row%orpb)*osub + coff + col*cscale.
// OMODE: 0 fp32, 1 split, 2 both.
// Tile 64(M) x 128(N) x 32(K); 256 thr = 4 waves; wave w covers cols [w*32, w*32+32).
// LDS: A(hi,lo) 64x32, W(hi,lo) 128x32 shorts, k-group XOR-swizzled (kg ^ ((row>>1)&3))
// via pre-swizzled GLOBAL source (LDS write linear) + swizzled ds_read slot.
template<int ACT, bool RES, int OMODE>
__global__ __launch_bounds__(256)
void mml(const short* __restrict__ Ahi, const short* __restrict__ Alo,
         int lda, int arpb, long abst, long aoff,
         long az1b, long az1, long az2, int zdiv2, int zdiv,
         const short* __restrict__ Whi, const short* __restrict__ Wlo,
         long woff, int ldw, long wz1b, long wz1, long wz2,
         const float* __restrict__ bias, long boff, float scale,
         float* __restrict__ Cout, short* __restrict__ Ohi, short* __restrict__ Olo,
         long oz1b, long oz1, long oz2,
         int orpb, long ostride, long osub, long coff, long cscale,
         const float* __restrict__ res,
         int M, int N, int K)
{
    __shared__ __align__(16) short LDS[12288];   // Ah 2048 | Al 2048 | Wh 4096 | Wl 4096
    short* Ah = LDS;
    short* Al = LDS + 2048;
    short* Wh = LDS + 4096;
    short* Wl = LDS + 8192;

    const int tid = threadIdx.x;
    const int wv = tid >> 6, l = tid & 63, q = l >> 4, ln = l & 15;
    const int n0 = blockIdx.x * 128 + wv * 32;
    const int m0 = blockIdx.y * 64;
    const int z = blockIdx.z;
    int zh_all = z / zdiv, zl = z - zh_all * zdiv;
    int zt = zh_all / zdiv2, zh = zh_all - zt * zdiv2;
    long ab = (long)zt * az1b + (long)zh * az1 + (long)zl * az2;
    long wb = (long)zt * wz1b + (long)zh * wz1 + (long)zl * wz2;
    long ob = (long)zt * oz1b + (long)zh * oz1 + (long)zl * oz2;

    // --- staging source offsets (pre-swizzled k-group) ---
    int trow = tid >> 2, tkg = tid & 3;
    int rA = m0 + trow; if (rA > M - 1) rA = M - 1;
    long aof = ab + aoff + (long)(rA / arpb) * abst + (long)(rA % arpb) * lda
             + (long)((tkg ^ ((trow >> 1) & 3)) * 8);
    int rw0 = tid >> 2, rw1 = (tid + 256) >> 2;
    int c0 = blockIdx.x * 128 + rw0; if (c0 > N - 1) c0 = N - 1;
    int c1 = blockIdx.x * 128 + rw1; if (c1 > N - 1) c1 = N - 1;
    long wof0 = woff + wb + (long)c0 * ldw + (long)(((tid & 3) ^ ((rw0 >> 1) & 3)) * 8);
    long wof1 = woff + wb + (long)c1 * ldw + (long)(((tid & 3) ^ ((rw1 >> 1) & 3)) * 8);

    // LDS dest bases (wave-uniform; lane*16B implicit)
    short* dAh  = Ah + wv * 512;
    short* dAl  = Al + wv * 512;
    short* dWh0 = Wh + wv * 512;
    short* dWh1 = Wh + 2048 + wv * 512;
    short* dWl0 = Wl + wv * 512;
    short* dWl1 = Wl + 2048 + wv * 512;

    // --- fragment read offsets (shorts), swizzled slot ---
    int sl8 = (q ^ ((ln >> 1) & 3)) * 8;
    int aoA[4], woW[2];
#pragma unroll
    for (int mf = 0; mf < 4; mf++) aoA[mf] = (mf * 16 + ln) * 32 + sl8;
#pragma unroll
    for (int nf = 0; nf < 2; nf++) woW[nf] = (wv * 32 + nf * 16 + ln) * 32 + sl8;

    f4v acc[4][2];
#pragma unroll
    for (int mf = 0; mf < 4; mf++)
#pragma unroll
        for (int nf = 0; nf < 2; nf++)
#pragma unroll
            for (int r = 0; r < 4; r++) acc[mf][nf][r] = 0.f;

    for (int kt = 0; kt < K; kt += 32) {
        __syncthreads();                       // previous tile fully consumed
        gld16(Ahi + aof + kt, dAh);
        gld16(Alo + aof + kt, dAl);
        gld16(Whi + wof0 + kt, dWh0);
        gld16(Whi + wof1 + kt, dWh1);
        gld16(Wlo + wof0 + kt, dWl0);
        gld16(Wlo + wof1 + kt, dWl1);
        __syncthreads();                       // drains vmcnt -> LDS ready

        s8v ah[4], al[4], bh[2], bl[2];
#pragma unroll
        for (int mf = 0; mf < 4; mf++) {
            ah[mf] = *(const s8v*)(&Ah[aoA[mf]]);
            al[mf] = *(const s8v*)(&Al[aoA[mf]]);
        }
#pragma unroll
        for (int nf = 0; nf < 2; nf++) {
            bh[nf] = *(const s8v*)(&Wh[woW[nf]]);
            bl[nf] = *(const s8v*)(&Wl[woW[nf]]);
        }
#pragma unroll
        for (int mf = 0; mf < 4; mf++)
#pragma unroll
            for (int nf = 0; nf < 2; nf++) {
                acc[mf][nf] = __builtin_amdgcn_mfma_f32_16x16x32_bf16(ah[mf], bh[nf], acc[mf][nf], 0, 0, 0);
                acc[mf][nf] = __builtin_amdgcn_mfma_f32_16x16x32_bf16(ah[mf], bl[nf], acc[mf][nf], 0, 0, 0);
                acc[mf][nf] = __builtin_amdgcn_mfma_f32_16x16x32_bf16(al[mf], bh[nf], acc[mf][nf], 0, 0, 0);
            }
    }

#pragma unroll
    for (int mf = 0; mf < 4; mf++) {
#pragma unroll
        for (int r = 0; r < 4; r++) {
            int row = m0 + mf * 16 + q * 4 + r;
            if (row >= M) continue;
#pragma unroll
            for (int nf = 0; nf < 2; nf++) {
                int col = n0 + nf * 16 + ln;
                if (col >= N) continue;
                float v = acc[mf][nf][r];
                v *= scale;
                if (bias) v += bias[boff + col];
                if (ACT) v = fmaxf(v, 0.f);
                if (RES) v += res[(size_t)(row >> 3) * 768 + col];
                long o = ob + (long)(row / orpb) * ostride + (long)(row % orpb) * osub
                       + coff + (long)col * cscale;
                if (OMODE == 0 || OMODE == 2) Cout[o] = v;
                if (OMODE >= 1) { short h, lo2; split1(v, h, lo2); Ohi[o] = h; Olo[o] = lo2; }
            }
        }
    }
}

// ===== direct-global fallback (used only for pre-L1 when workspace can't hold split W1) =====
template<int ACT, bool RES, int OMODE, bool WSPLIT>
__global__ __launch_bounds__(256)
void mm(const short* __restrict__ Ahi, const short* __restrict__ Alo,
        int lda, int arpb, long abst, long aoff,
        long az1b, long az1, long az2, int zdiv2, int zdiv,
        const short* __restrict__ Whi, const short* __restrict__ Wlo,
        const float* __restrict__ Wf,
        long woff, int ldw, long wz1b, long wz1, long wz2,
        const float* __restrict__ bias, long boff, float scale,
        float* __restrict__ Cout, short* __restrict__ Ohi, short* __restrict__ Olo,
        long oz1b, long oz1, long oz2,
        int orpb, long ostride, long osub, long coff, long cscale,
        const float* __restrict__ res,
        int M, int N, int K)
{
    const int tid = threadIdx.x;
    const int w = tid >> 6, l = tid & 63, q = l >> 4, ln = l & 15;
    const int n0 = blockIdx.x * 128 + w * 32;
    const int m0 = blockIdx.y * 64;
    const int z = blockIdx.z;
    int zh_all = z / zdiv, zl = z - zh_all * zdiv;
    int zt = zh_all / zdiv2, zh = zh_all - zt * zdiv2;
    long ab = (long)zt * az1b + (long)zh * az1 + (long)zl * az2;
    long wb = (long)zt * wz1b + (long)zh * wz1 + (long)zl * wz2;
    long ob = (long)zt * oz1b + (long)zh * oz1 + (long)zl * oz2;

    long aofs[4];
#pragma unroll
    for (int mf = 0; mf < 4; mf++) {
        int rm = m0 + mf * 16 + ln;
        if (rm > M - 1) rm = M - 1;
        aofs[mf] = ab + aoff + (long)(rm / arpb) * abst + (long)(rm % arpb) * lda + q * 8;
    }
    long wofs[2];
#pragma unroll
    for (int nf = 0; nf < 2; nf++)
        wofs[nf] = woff + wb + (long)(n0 + nf * 16 + ln) * ldw + q * 8;

    f4v acc[4][2];
#pragma unroll
    for (int mf = 0; mf < 4; mf++)
#pragma unroll
        for (int nf = 0; nf < 2; nf++)
#pragma unroll
            for (int r = 0; r < 4; r++) acc[mf][nf][r] = 0.f;

#pragma unroll 2
    for (int k = 0; k < K; k += 32) {
        s8v ah[4], al[4], bh[2], bl[2];
#pragma unroll
        for (int mf = 0; mf < 4; mf++) {
            ah[mf] = *(const s8v*)(const void*)(Ahi + aofs[mf] + k);
            al[mf] = *(const s8v*)(const void*)(Alo + aofs[mf] + k);
        }
#pragma unroll
        for (int nf = 0; nf < 2; nf++) {
            if (WSPLIT) {
                bh[nf] = *(const s8v*)(const void*)(Whi + wofs[nf] + k);
                bl[nf] = *(const s8v*)(const void*)(Wlo + wofs[nf] + k);
            } else {
                f8v wv = *(const f8v*)(const void*)(Wf + wofs[nf] + k);
                split8(wv, bh[nf], bl[nf]);
            }
        }
#pragma unroll
        for (int mf = 0; mf < 4; mf++)
#pragma unroll
            for (int nf = 0; nf < 2; nf++) {
                acc[mf][nf] = __builtin_amdgcn_mfma_f32_16x16x32_bf16(ah[mf], bh[nf], acc[mf][nf], 0, 0, 0);
                acc[mf][nf] = __builtin_amdgcn_mfma_f32_16x16x32_bf16(ah[mf], bl[nf], acc[mf][nf], 0, 0, 0);
                acc[mf][nf] = __builtin_amdgcn_mfma_f32_16x16x32_bf16(al[mf], bh[nf], acc[mf][nf], 0, 0, 0);
            }
    }

#pragma unroll
    for (int mf = 0; mf < 4; mf++) {
#pragma unroll
        for (int r = 0; r < 4; r++) {
            int row = m0 + mf * 16 + q * 4 + r;
            if (row >= M) continue;
#pragma unroll
            for (int nf = 0; nf < 2; nf++) {
                int col = n0 + nf * 16 + ln;
                if (col >= N) continue;
                float v = acc[mf][nf][r];
                v *= scale;
                if (bias) v += bias[boff + col];
                if (ACT) v = fmaxf(v, 0.f);
                if (RES) v += res[(size_t)(row >> 3) * 768 + col];
                long o = ob + (long)(row / orpb) * ostride + (long)(row % orpb) * osub
                       + coff + (long)col * cscale;
                if (OMODE == 0 || OMODE == 2) Cout[o] = v;
                if (OMODE >= 1) { short h, lo2; split1(v, h, lo2); Ohi[o] = h; Olo[o] = lo2; }
            }
        }
    }
}

// row-wise in-place softmax; also emits split(hi,lo); grid.x = #rows, 256 threads
__global__ void softmax_rows(float* __restrict__ sc, short* __restrict__ hi,
                             short* __restrict__ lo, int len)
{
    size_t base = (size_t)blockIdx.x * len;
    float* p = sc + base;
    __shared__ float red[256];
    int tid = threadIdx.x;
    float m = -1e30f;
    for (int i = tid; i < len; i += 256) m = fmaxf(m, p[i]);
    red[tid] = m; __syncthreads();
    for (int o = 128; o > 0; o >>= 1) {
        if (tid < o) red[tid] = fmaxf(red[tid], red[tid + o]);
        __syncthreads();
    }
    float mx = red[0]; __syncthreads();
    float s = 0.f;
    for (int i = tid; i < len; i += 256) { float e = expf(p[i] - mx); p[i] = e; s += e; }
    red[tid] = s; __syncthreads();
    for (int o = 128; o > 0; o >>= 1) {
        if (tid < o) red[tid] += red[tid + o];
        __syncthreads();
    }
    float inv = 1.f / red[0]; __syncthreads();
    for (int i = tid; i < len; i += 256) {
        float v = p[i] * inv;
        p[i] = v;
        short h, l2; split1(v, h, l2);
        hi[base + i] = h; lo[base + i] = l2;
    }
}

// wmask over chunk: block z = tch*8 + b; sc2 laid [tch][b][h][8][128]; split output
__global__ void wmask_kernel(const float* __restrict__ sc2, short* __restrict__ wh,
                             short* __restrict__ wl)
{
    int z = blockIdx.x;
    const float* src = sc2 + (size_t)z * 12288;
    for (int idx = threadIdx.x; idx < 1024; idx += 256) {
        float s = 0.f;
        for (int h = 0; h < NH_; h++) s += src[h * 1024 + idx];
        float v = s * (1.f / 12.f);
        short h2, l2; split1(v, h2, l2);
        wh[(size_t)z * 1024 + idx] = h2;
        wl[(size_t)z * 1024 + idx] = l2;
    }
}

// GRU states for all 8 candidate predecessors of every (t, b, a); split output.
// chunk rows: R = tloc*512 + b*64 + ap*8 + a
__global__ void gru_cand(const float* __restrict__ gi_all, const float* __restrict__ ghall,
                         const float* __restrict__ gh0, const float* __restrict__ pre_all,
                         const float* __restrict__ s0p,
                         short* __restrict__ sh, short* __restrict__ sl, int t0c)
{
    long idx = (long)blockIdx.x * 256 + threadIdx.x;   // exactly nt*512*768
    int c = (int)(idx % 768);
    long r = idx / 768;
    int tloc = (int)(r / 512), rem = (int)(r % 512);
    int b = rem >> 6, ap = (rem >> 3) & 7, a = rem & 7;
    int t = t0c + tloc;
    const float* gi = gi_all + ((long)t * 64 + b * 8 + a) * 2304;
    const float* gh; float hv;
    if (t == 0) { gh = gh0; hv = s0p[c]; }
    else {
        long j = (long)(t - 1) * 64 + b * 8 + ap;
        gh = ghall + j * 2304;
        hv = pre_all[j * 768 + c];
    }
    float ir  = gi[c], iz = gi[768 + c], inn = gi[1536 + c];
    float rg = 1.f / (1.f + expf(-(ir + gh[c])));
    float zg = 1.f / (1.f + expf(-(iz + gh[768 + c])));
    float ng = tanhf(inn + rg * gh[1536 + c]);
    float v = (1.f - zg) * ng + zg * hv;
    short h2, l2; split1(v, h2, l2);
    sh[idx] = h2; sl[idx] = l2;
}

// logits for candidate rows: lc[t0c*512 + blk*64 + r] = s1H_row . w2 + b2
__global__ void logits_cand_k(const float* __restrict__ s1H, const float* __restrict__ w2,
                              const float* __restrict__ b2, float* __restrict__ lc, int t0c)
{
    __shared__ float red[256];
    int blk = blockIdx.x;
    int tid = threadIdx.x, r = tid >> 2, p = tid & 3;
    const float* rp = s1H + ((size_t)blk * 64 + r) * 768 + p * 192;
    const float* wp = w2 + p * 192;
    float s = 0.f;
    for (int i = 0; i < 192; i++) s = fmaf(rp[i], wp[i], s);
    red[tid] = s; __syncthreads();
    if (p == 0)
        lc[(size_t)t0c * 512 + (size_t)blk * 64 + r]
            = red[tid] + red[tid + 1] + red[tid + 2] + red[tid + 3] + b2[0];
}

// walk the argmax chain through the precomputed candidate-logits table; 64 threads
__global__ void chain_k(const float* __restrict__ lc, float* __restrict__ out)
{
    __shared__ float lrow[64];
    __shared__ int am[8];
    int tid = threadIdx.x;            // b*8 + a
    int b = tid >> 3, a = tid & 7;
    for (int t = 0; t < T_; t++) {
        int cand = (t == 0) ? 0 : am[b];
        float v = lc[t * 512 + b * 64 + cand * 8 + a];
        out[((size_t)(b * T_ + t)) * A_ + a] = v;
        lrow[tid] = v;
        __syncthreads();
        if (a == 0) {
            float best = lrow[b * 8]; int bi = 0;
            for (int x = 1; x < 8; x++) { float w = lrow[b * 8 + x]; if (w > best) { best = w; bi = x; } }
            am[b] = bi;
        }
        __syncthreads();
    }
}

// ===== host =====
struct SB { short* h; short* l; };

template<int ACT, int OM>
static inline void MMs(hipStream_t st, SB A, int lda, int arpb, long abst, long aoff,
                       SB W, long woff, int ldw, const float* bias, long boff,
                       float* Cf, SB O, long ldc, long coff, int M, int N, int K)
{
    dim3 g((unsigned)((N + 127) / 128), (unsigned)((M + 63) / 64), 1), b(256);
    mml<ACT, false, OM><<<g, b, 0, st>>>(A.h, A.l, lda, arpb, abst, aoff,
        0, 0, 0, NP, 1, W.h, W.l, woff, ldw, 0, 0, 0,
        bias, boff, 1.f, Cf, O.h, O.l, 0, 0, 0, 1, ldc, 0, coff, 1, nullptr, M, N, K);
}

extern "C" void kernel_launch(void* const* d_in, const int* in_sizes, int n_in,
                              void* d_out, int out_size, void* d_ws, size_t ws_size,
                              hipStream_t stream)
{
    const float* video     = (const float*)d_in[0];
    const float* script    = (const float*)d_in[1];
    const float* question  = (const float*)d_in[2];
    const float* a_texts   = (const float*)d_in[3];
    const float* a_buttons = (const float*)d_in[4];
    const float* state0    = (const float*)d_in[5];
    const float* mlp_v_w1 = (const float*)d_in[6];  const float* mlp_v_b1 = (const float*)d_in[7];
    const float* mlp_v_w2 = (const float*)d_in[8];  const float* mlp_v_b2 = (const float*)d_in[9];
    const float* mlp_t_w1 = (const float*)d_in[10]; const float* mlp_t_b1 = (const float*)d_in[11];
    const float* mlp_t_w2 = (const float*)d_in[12]; const float* mlp_t_b2 = (const float*)d_in[13];
    const float* pre_w1   = (const float*)d_in[14]; const float* pre_b1   = (const float*)d_in[15];
    const float* pre_w2   = (const float*)d_in[16]; const float* pre_b2   = (const float*)d_in[17];
    const float* s2v_in_w = (const float*)d_in[18]; const float* s2v_in_b = (const float*)d_in[19];
    const float* s2v_out_w= (const float*)d_in[20]; const float* s2v_out_b= (const float*)d_in[21];
    const float* qa2s_in_w= (const float*)d_in[22]; const float* qa2s_in_b= (const float*)d_in[23];
    const float* qa2s_out_w=(const float*)d_in[24]; const float* qa2s_out_b=(const float*)d_in[25];
    const float* gru_w_ih = (const float*)d_in[26]; const float* gru_w_hh = (const float*)d_in[27];
    const float* gru_b_ih = (const float*)d_in[28]; const float* gru_b_hh = (const float*)d_in[29];
    const float* proj_w1  = (const float*)d_in[30]; const float* proj_b1  = (const float*)d_in[31];
    const float* proj_w2  = (const float*)d_in[32]; const float* proj_b2  = (const float*)d_in[33];
    float* out = (float*)d_out;
    (void)in_sizes; (void)n_in; (void)out_size;

    hipStream_t st = stream;
    dim3 blk(256);
    const long DDL = 589824;

    // ---- workspace bump allocator (units of 4 bytes) ----
    float* fb = (float*)d_ws;
    auto take = [&](long n) { float* p = fb; fb += n; return p; };
    auto mksb = [&](long n) { float* p = take(n); SB s; s.h = (short*)p; s.l = s.h + n; return s; };

    // split weights (persistent)
    SB w_v1 = mksb(589824),  w_v2 = mksb(589824);
    SB w_t1 = mksb(589824),  w_t2 = mksb(589824);
    SB s2vi = mksb(1769472), s2vo = mksb(589824);
    SB qa2i = mksb(1769472), qa2o = mksb(589824);
    SB gih  = mksb(1769472), ghh  = mksb(1769472);
    SB pj1  = mksb(589824),  pw2  = mksb(4718592);
    // split inputs
    SB sVid = mksb(3145728), sScr = mksb(786432), sQue = mksb(6144);
    SB sAtx = mksb(786432),  sAbt = mksb(3932160), sS0 = mksb(768);
    // persistent activations
    SB svat = mksb(786432), sk2 = mksb(786432), sv2T = mksb(786432);
    float* q_t     = take(6144);
    float* gh0     = take(2304);
    float* pre_all = take(786432);
    SB spre        = mksb(786432);
    float* lc      = take(8192);

    long wsF = (long)(ws_size / 4);
    long dynMin = 5505024;
    bool w1split = ((fb - (float*)d_ws) + 37748736L + dynMin + 64) <= wsF;
    SB pw1s = { nullptr, nullptr };
    if (w1split) pw1s = mksb(37748736);

    float* U = fb;
    long dynF = wsF - (fb - (float*)d_ws) - 64;

    int g = 1;
    for (int c = 8; c >= 1; c >>= 1) { if (1572864L + (long)c * 2752512L <= dynF) { g = c; break; } }
    int TG = 1;
    for (int c = 16; c >= 1; c >>= 1) { if ((long)c * 1384448L <= dynF) { TG = c; break; } }
    int TG2 = 1;
    for (int c = 16; c >= 1; c >>= 1) { if (4718592L + (long)c * 786432L <= dynF) { TG2 = c; break; } }

    // ---- conversions ----
    auto SPL = [&](const float* x, SB s, long n) {
        long n8 = n / 8;
        split_arr<<<dim3((unsigned)((n8 + 255) / 256)), blk, 0, st>>>(x, s.h, s.l, n8);
    };
    SPL(mlp_v_w1, w_v1, 589824);  SPL(mlp_v_w2, w_v2, 589824);
    SPL(mlp_t_w1, w_t1, 589824);  SPL(mlp_t_w2, w_t2, 589824);
    SPL(s2v_in_w, s2vi, 1769472); SPL(s2v_out_w, s2vo, 589824);
    SPL(qa2s_in_w, qa2i, 1769472);SPL(qa2s_out_w, qa2o, 589824);
    SPL(gru_w_ih, gih, 1769472);  SPL(gru_w_hh, ghh, 1769472);
    SPL(proj_w1, pj1, 589824);    SPL(pre_w2, pw2, 4718592);
    SPL(video, sVid, 3145728);    SPL(script, sScr, 786432);
    SPL(question, sQue, 6144);    SPL(a_texts, sAtx, 786432);
    SPL(a_buttons, sAbt, 3932160);SPL(state0, sS0, 768);
    if (w1split) SPL(pre_w1, pw1s, 37748736);

    // ======== phase 1 ========
    // phase-1 view of U
    SB sqp   = { (short*)U, (short*)U + 786432 };
    SB satt  = { (short*)(U + 786432), (short*)(U + 786432) + 786432 };
    float* G0 = U + 1572864;
    SB sbufA = { (short*)G0, (short*)G0 + (long)g * 393216 };
    SB sbufB = { (short*)(G0 + (long)g * 393216), (short*)(G0 + (long)g * 393216) + (long)g * 393216 };
    SB sbufD = { (short*)(G0 + 2L * g * 393216), (short*)(G0 + 2L * g * 393216) + (long)g * 393216 };
    float* sc_g = G0 + 3L * g * 393216;
    SB ssc_g = { (short*)(sc_g + (long)g * 786432), (short*)(sc_g + (long)g * 786432) + (long)g * 786432 };
    SB sscrH = { (short*)G0, (short*)G0 + 786432 };
    SB sscrT = { (short*)(G0 + 786432), (short*)(G0 + 786432) + 786432 };
    SB sqH   = { (short*)(G0 + 1572864), (short*)(G0 + 1572864) + 6144 };

    MMs<0, 1>(st, sScr, D_, NP, 0, 0, s2vi, 0, D_, s2v_in_b, 0, nullptr, sqp, D_, 0, 1024, D_, D_);
    for (int s0 = 0; s0 < B_; s0 += g) {
        int Mg = 512 * g;
        long voff = (long)s0 * 393216;
        MMs<1, 1>(st, sVid, D_, NP, 0, voff, w_v1, 0, D_, mlp_v_b1, 0, nullptr, sbufA, D_, 0, Mg, D_, D_);
        MMs<0, 1>(st, sbufA, D_, NP, 0, 0, w_v2, 0, D_, mlp_v_b2, 0, nullptr, sbufB, D_, 0, Mg, D_, D_);
        MMs<0, 1>(st, sbufB, D_, NP, 0, 0, s2vi, DDL, D_, s2v_in_b, D_, nullptr, sbufA, D_, 0, Mg, D_, D_); // kp
        {   // vpT: out o = (row/512)*393216 + row%512 + col*512
            dim3 gr(6, (unsigned)(Mg / 64), 1);
            mml<0, false, 1><<<gr, blk, 0, st>>>(sbufB.h, sbufB.l, D_, NP, 0, 0, 0, 0, 0, NP, 1,
                s2vi.h, s2vi.l, 2 * DDL, D_, 0, 0, 0, s2v_in_b, 2 * D_, 1.f,
                nullptr, sbufD.h, sbufD.l, 0, 0, 0, 512, 393216, 1, 0, 512, nullptr, Mg, D_, D_);
        }
        {   // scores (fp32): sc_g[z=lb*12+h][i][j] = 0.125 * qp_i . kp_j (dh slice h)
            dim3 gr(4, 2, (unsigned)(12 * g));
            mml<0, false, 0><<<gr, blk, 0, st>>>(sqp.h, sqp.l, D_, NP, 0, (long)s0 * 98304,
                0, 98304, 64, NP, 12,
                sbufA.h, sbufA.l, 0, D_, 0, 393216, 64, nullptr, 0, 0.125f,
                sc_g, nullptr, nullptr, 0, 786432, 65536, 1, 512, 0, 0, 1, nullptr, S_, V_, 64);
        }
        softmax_rows<<<dim3((unsigned)(12 * g * 128)), blk, 0, st>>>(sc_g, ssc_g.h, ssc_g.l, 512);
        {   // PV: attnout[b*128+i][h*64+d] = P . V
            dim3 gr(1, 2, (unsigned)(12 * g));
            mml<0, false, 1><<<gr, blk, 0, st>>>(ssc_g.h, ssc_g.l, 512, NP, 0, 0,
                0, 786432, 65536, NP, 12,
                sbufD.h, sbufD.l, 0, 512, 0, 393216, 32768, nullptr, 0, 1.f,
                nullptr, satt.h, satt.l, 0, 98304, 64, 1, 768, 0, (long)s0 * 98304, 1, nullptr, S_, 64, 512);
        }
    }
    {   // vid_attT: out o = (row/128)*98304 + row%128 + col*128
        dim3 gr(6, 16, 1);
        mml<0, false, 1><<<gr, blk, 0, st>>>(satt.h, satt.l, D_, NP, 0, 0, 0, 0, 0, NP, 1,
            s2vo.h, s2vo.l, 0, D_, 0, 0, 0, s2v_out_b, 0, 1.f,
            nullptr, svat.h, svat.l, 0, 0, 0, 128, 98304, 1, 0, 128, nullptr, 1024, D_, D_);
    }
    MMs<1, 1>(st, sScr, D_, NP, 0, 0, w_t1, 0, D_, mlp_t_b1, 0, nullptr, sscrH, D_, 0, 1024, D_, D_);
    MMs<0, 1>(st, sscrH, D_, NP, 0, 0, w_t2, 0, D_, mlp_t_b2, 0, nullptr, sscrT, D_, 0, 1024, D_, D_);
    MMs<0, 1>(st, sscrT, D_, NP, 0, 0, qa2i, DDL, D_, qa2s_in_b, D_, nullptr, sk2, D_, 0, 1024, D_, D_);
    {   // v2T: out o = (row/128)*98304 + row%128 + col*128
        dim3 gr(6, 16, 1);
        mml<0, false, 1><<<gr, blk, 0, st>>>(sscrT.h, sscrT.l, D_, NP, 0, 0, 0, 0, 0, NP, 1,
            qa2i.h, qa2i.l, 2 * DDL, D_, 0, 0, 0, qa2s_in_b, 2 * D_, 1.f,
            nullptr, sv2T.h, sv2T.l, 0, 0, 0, 128, 98304, 1, 0, 128, nullptr, 1024, D_, D_);
    }
    MMs<1, 1>(st, sQue, D_, NP, 0, 0, w_t1, 0, D_, mlp_t_b1, 0, nullptr, sqH, D_, 0, B_, D_, D_);
    MMs<0, 0>(st, sqH, D_, NP, 0, 0, w_t2, 0, D_, mlp_t_b2, 0, q_t, SB{nullptr, nullptr}, D_, 0, B_, D_, D_);

    // ======== batched scan precompute (chunks of TG timesteps) ========
    for (int t0 = 0; t0 < T_; t0 += TG) {
        float* p = U;
        SB sinp  = { (short*)p, (short*)p + (long)TG * 393216 }; p += (long)TG * 393216;
        SB spreH = { (short*)p, (short*)p + (long)TG * 393216 }; p += (long)TG * 393216;
        SB satH  = { (short*)p, (short*)p + (long)TG * 49152 };  p += (long)TG * 49152;
        SB sabH  = { (short*)p, (short*)p + (long)TG * 245760 }; p += (long)TG * 245760;
        SB sqp2  = { (short*)p, (short*)p + (long)TG * 49152 };  p += (long)TG * 49152;
        float* sc2 = p;                                          p += (long)TG * 98304;
        SB ssc2  = { (short*)p, (short*)p + (long)TG * 98304 };  p += (long)TG * 98304;
        SB swm   = { (short*)p, (short*)p + (long)TG * 8192 };   p += (long)TG * 8192;
        SB satt2 = { (short*)p, (short*)p + (long)TG * 49152 };  p += (long)TG * 49152;

        // a_t layer1 (gather over t), z = tch
        mml<1, false, 1><<<dim3(6, 1, TG), blk, 0, st>>>(sAtx.h, sAtx.l, D_, A_, 98304,
            (long)t0 * 6144, 0, 6144, 0, NP, 1,
            w_t1.h, w_t1.l, 0, D_, 0, 0, 0, mlp_t_b1, 0, 1.f,
            nullptr, satH.h, satH.l, 0, 49152, 0, 1, 768, 0, 0, 1, nullptr, 64, D_, D_);
        // a_t layer2 + q_t -> inputs[:,1536:2304]
        mml<0, true, 1><<<dim3(6, 1, TG), blk, 0, st>>>(satH.h, satH.l, D_, NP, 0, 0,
            0, 49152, 0, NP, 1,
            w_t2.h, w_t2.l, 0, D_, 0, 0, 0, mlp_t_b2, 0, 1.f,
            nullptr, sinp.h, sinp.l, 0, 393216, 0, 1, DIN_, 0, 1536, 1, q_t, 64, D_, D_);
        // a_b layer1 (gather over t)
        mml<1, false, 1><<<dim3(6, 5, TG), blk, 0, st>>>(sAbt.h, sAbt.l, D_, A_ * M_, 491520,
            (long)t0 * 30720, 0, 30720, 0, NP, 1,
            w_v1.h, w_v1.l, 0, D_, 0, 0, 0, mlp_v_b1, 0, 1.f,
            nullptr, sabH.h, sabH.l, 0, 245760, 0, 1, 768, 0, 0, 1, nullptr, 320, D_, D_);
        // a_b layer2 -> inputs[:,2304:6144]
        mml<0, false, 1><<<dim3(6, 5, TG), blk, 0, st>>>(sabH.h, sabH.l, D_, NP, 0, 0,
            0, 245760, 0, NP, 1,
            w_v2.h, w_v2.l, 0, D_, 0, 0, 0, mlp_v_b2, 0, 1.f,
            nullptr, sinp.h, sinp.l, 0, 393216, 0, M_, DIN_, 768, 2304, 1, nullptr, 320, D_, D_);
        // qp2 = qa @ qa2s_wq
        mml<0, false, 1><<<dim3(6, 1, TG), blk, 0, st>>>(sinp.h, sinp.l, DIN_, NP, 0, 1536,
            0, 393216, 0, NP, 1,
            qa2i.h, qa2i.l, 0, D_, 0, 0, 0, qa2s_in_b, 0, 1.f,
            nullptr, sqp2.h, sqp2.l, 0, 49152, 0, 1, 768, 0, 0, 1, nullptr, 64, D_, D_);
        // scores2 (fp32): z = tch*96 + b*12 + h
        mml<0, false, 0><<<dim3(1, 1, 96 * TG), blk, 0, st>>>(sqp2.h, sqp2.l, D_, NP, 0, 0,
            49152, 6144, 64, 8, 12,
            sk2.h, sk2.l, 0, D_, 0, 98304, 64, nullptr, 0, 0.125f,
            sc2, nullptr, nullptr, 98304, 12288, 1024, 1, 128, 0, 0, 1, nullptr, A_, S_, 64);
        softmax_rows<<<dim3((unsigned)(768 * TG)), blk, 0, st>>>(sc2, ssc2.h, ssc2.l, 128);
        wmask_kernel<<<dim3((unsigned)(8 * TG)), blk, 0, st>>>(sc2, swm.h, swm.l);
        // qa_vid = wmask @ vid_att -> inputs[:,0:768]; z = tch*8 + b
        mml<0, false, 1><<<dim3(6, 1, 8 * TG), blk, 0, st>>>(swm.h, swm.l, S_, NP, 0, 0,
            0, 8192, 1024, NP, 8,
            svat.h, svat.l, 0, 128, 0, 0, 98304, nullptr, 0, 1.f,
            nullptr, sinp.h, sinp.l, 0, 393216, 49152, 1, DIN_, 0, 0, 1, nullptr, A_, D_, S_);
        // PV2 -> att2; z = tch*96 + b*12 + h
        mml<0, false, 1><<<dim3(1, 1, 96 * TG), blk, 0, st>>>(ssc2.h, ssc2.l, S_, NP, 0, 0,
            98304, 12288, 1024, 8, 12,
            sv2T.h, sv2T.l, 0, 128, 0, 98304, 8192, nullptr, 0, 1.f,
            nullptr, satt2.h, satt2.l, 49152, 6144, 64, 1, 768, 0, 0, 1, nullptr, A_, 64, S_);
        // attn out-proj -> inputs[:,768:1536]
        mml<0, false, 1><<<dim3(6, 1, TG), blk, 0, st>>>(satt2.h, satt2.l, D_, NP, 0, 0,
            0, 49152, 0, NP, 1,
            qa2o.h, qa2o.l, 0, D_, 0, 0, 0, qa2s_out_b, 0, 1.f,
            nullptr, sinp.h, sinp.l, 0, 393216, 0, 1, DIN_, 0, 768, 1, nullptr, 64, D_, D_);
        // pre-MLP L1 (the big batched GEMM): M = TG*64
        if (w1split)
            mml<1, false, 1><<<dim3(48, TG, 1), blk, 0, st>>>(sinp.h, sinp.l, DIN_, NP, 0, 0,
                0, 0, 0, NP, 1,
                pw1s.h, pw1s.l, 0, DIN_, 0, 0, 0, pre_b1, 0, 1.f,
                nullptr, spreH.h, spreH.l, 0, 0, 0, 1, DIN_, 0, 0, 1, nullptr, TG * 64, DIN_, DIN_);
        else
            mm<1, false, 1, false><<<dim3(48, TG, 1), blk, 0, st>>>(sinp.h, sinp.l, DIN_, NP, 0, 0,
                0, 0, 0, NP, 1,
                nullptr, nullptr, pre_w1, 0, DIN_, 0, 0, 0, pre_b1, 0, 1.f,
                nullptr, spreH.h, spreH.l, 0, 0, 0, 1, DIN_, 0, 0, 1, nullptr, TG * 64, DIN_, DIN_);
        // pre-MLP L2 -> pre_all (fp32 + split)
        mml<0, false, 2><<<dim3(6, TG, 1), blk, 0, st>>>(spreH.h, spreH.l, DIN_, NP, 0, 0,
            0, 0, 0, NP, 1,
            pw2.h, pw2.l, 0, DIN_, 0, 0, 0, pre_b2, 0, 1.f,
            pre_all, spre.h, spre.l, 0, 0, 0, 1, 768, 0, (long)t0 * 49152, 1, nullptr, TG * 64, DS_, DIN_);
    }

    // ======== GRU candidate precompute ========
    float* gi_all = U;
    float* ghall  = U + 2359296;
    float* candU  = U + 4718592;
    MMs<0, 0>(st, spre, DS_, NP, 0, 0, gih, 0, DS_, gru_b_ih, 0, gi_all, SB{nullptr, nullptr}, 3 * DS_, 0, 1024, 3 * DS_, DS_);
    MMs<0, 0>(st, spre, DS_, NP, 0, 0, ghh, 0, DS_, gru_b_hh, 0, ghall, SB{nullptr, nullptr}, 3 * DS_, 0, 1024, 3 * DS_, DS_);
    MMs<0, 0>(st, sS0, DS_, NP, 0, 0, ghh, 0, DS_, gru_b_hh, 0, gh0, SB{nullptr, nullptr}, 3 * DS_, 0, 1, 3 * DS_, DS_);

    for (int t0 = 0; t0 < T_; t0 += TG2) {
        float* p = candU;
        SB sstc = { (short*)p, (short*)p + (long)TG2 * 393216 };
        float* s1H = p + (long)TG2 * 393216;
        gru_cand<<<dim3((unsigned)(TG2 * 1536)), blk, 0, st>>>(gi_all, ghall, gh0, pre_all,
                                                               state0, sstc.h, sstc.l, t0);
        MMs<1, 0>(st, sstc, DS_, NP, 0, 0, pj1, 0, DS_, proj_b1, 0, s1H, SB{nullptr, nullptr}, DS_, 0, TG2 * 512, DS_, DS_);
        logits_cand_k<<<dim3((unsigned)(TG2 * 8)), blk, 0, st>>>(s1H, proj_w2, proj_b2, lc, t0);
    }

    // ======== sequential argmax chain (trivial) ========
    chain_k<<<1, 64, 0, st>>>(lc, out);
}

// Round 6
// 1638.947 us; speedup vs baseline: 1.9719x; 1.1043x over previous
//
#include <hip/hip_runtime.h>
#include <hip/hip_bf16.h>
#include <math.h>

typedef short s8v __attribute__((ext_vector_type(8)));
typedef float f4v __attribute__((ext_vector_type(4)));
typedef float f8v __attribute__((ext_vector_type(8)));

#define D_    768
#define M_    5
#define DS_   768
#define NH_   12
#define B_    8
#define V_    512
#define S_    128
#define T_    16
#define A_    8
#define DIN_  6144
#define NP    (1 << 30)

// split fp32 x into bf16 hi (truncate) + bf16 lo (truncate of exact residual)
__device__ __forceinline__ void split8(const f8v& x, s8v& hi, s8v& lo) {
#pragma unroll
    for (int j = 0; j < 8; j++) {
        unsigned xu = __float_as_uint(x[j]);
        float hf = __uint_as_float(xu & 0xFFFF0000u);
        float r  = x[j] - hf;                       // exact in fp32
        hi[j] = (short)(xu >> 16);
        lo[j] = (short)(__float_as_uint(r) >> 16);
    }
}

__device__ __forceinline__ void split1(float v, short& h, short& l) {
    unsigned xu = __float_as_uint(v);
    float hf = __uint_as_float(xu & 0xFFFF0000u);
    h = (short)(xu >> 16);
    l = (short)(__float_as_uint(v - hf) >> 16);
}

// async global->LDS, 16B per lane; LDS dest = wave-uniform base + lane*16
__device__ __forceinline__ void gld16(const short* g, short* l) {
    __builtin_amdgcn_global_load_lds(
        (const __attribute__((address_space(1))) unsigned int*)(g),
        (__attribute__((address_space(3))) unsigned int*)(l), 16, 0, 0);
}

// elementwise fp32 -> (hi,lo) bf16 pair conversion; n8 = n/8 vectors
__global__ void split_arr(const float* __restrict__ x, short* __restrict__ hi,
                          short* __restrict__ lo, long n8)
{
    long i = (long)blockIdx.x * 256 + threadIdx.x;
    if (i >= n8) return;
    f8v v = *(const f8v*)(x + i * 8);
    s8v h, l;
    split8(v, h, l);
    *(s8v*)(hi + i * 8) = h;
    *(s8v*)(lo + i * 8) = l;
}

// ===== LDS-staged split-bf16 MFMA GEMM, double-buffered 2-phase pipeline =====
// C = act(scale*(A @ W^T) + bias [+res]).  Addressing semantics unchanged:
// A row r: off = ab + aoff + (r/arpb)*abst + (r%arpb)*lda (+k).
// z: zh_all=z/zdiv, zl=z%zdiv, zt=zh_all/zdiv2, zh=zh_all%zdiv2;
//   ab=zt*az1b+zh*az1+zl*az2 (W: wz*, out: oz*). W row n: woff+wb+n*ldw.
// Out: ob + (row/orpb)*ostride + (row%orpb)*osub + coff + col*cscale.
// OMODE: 0 fp32, 1 split, 2 both.
// Tile 64(M) x 128(N) x 32(K); 256 thr = 4 waves; wave w covers cols [w*32, w*32+32).
// Per K-step: ONE barrier (drains vmcnt -> current buf ready, releases other buf),
// then async-stage NEXT tile into other buf, then ds_read+MFMA current.
// k-group XOR swizzle (kg ^ ((row>>1)&3)) via pre-swizzled GLOBAL source + read slot.
template<int ACT, bool RES, int OMODE>
__global__ __launch_bounds__(256)
void mml(const short* __restrict__ Ahi, const short* __restrict__ Alo,
         int lda, int arpb, long abst, long aoff,
         long az1b, long az1, long az2, int zdiv2, int zdiv,
         const short* __restrict__ Whi, const short* __restrict__ Wlo,
         long woff, int ldw, long wz1b, long wz1, long wz2,
         const float* __restrict__ bias, long boff, float scale,
         float* __restrict__ Cout, short* __restrict__ Ohi, short* __restrict__ Olo,
         long oz1b, long oz1, long oz2,
         int orpb, long ostride, long osub, long coff, long cscale,
         const float* __restrict__ res,
         int M, int N, int K)
{
    __shared__ __align__(16) short LDS[2][12288];  // per buf: Ah 2048|Al 2048|Wh 4096|Wl 4096

    const int tid = threadIdx.x;
    const int wv = tid >> 6, l = tid & 63, q = l >> 4, ln = l & 15;
    const int n0 = blockIdx.x * 128 + wv * 32;
    const int m0 = blockIdx.y * 64;
    const int z = blockIdx.z;
    int zh_all = z / zdiv, zl = z - zh_all * zdiv;
    int zt = zh_all / zdiv2, zh = zh_all - zt * zdiv2;
    long ab = (long)zt * az1b + (long)zh * az1 + (long)zl * az2;
    long wb = (long)zt * wz1b + (long)zh * wz1 + (long)zl * wz2;
    long ob = (long)zt * oz1b + (long)zh * oz1 + (long)zl * oz2;

    // --- staging source offsets (pre-swizzled k-group) ---
    int trow = tid >> 2, tkg = tid & 3;
    int rA = m0 + trow; if (rA > M - 1) rA = M - 1;
    long aof = ab + aoff + (long)(rA / arpb) * abst + (long)(rA % arpb) * lda
             + (long)((tkg ^ ((trow >> 1) & 3)) * 8);
    int rw0 = tid >> 2, rw1 = (tid + 256) >> 2;
    int c0 = blockIdx.x * 128 + rw0; if (c0 > N - 1) c0 = N - 1;
    int c1 = blockIdx.x * 128 + rw1; if (c1 > N - 1) c1 = N - 1;
    long wof0 = woff + wb + (long)c0 * ldw + (long)(((tid & 3) ^ ((rw0 >> 1) & 3)) * 8);
    long wof1 = woff + wb + (long)c1 * ldw + (long)(((tid & 3) ^ ((rw1 >> 1) & 3)) * 8);

    // stage tile at k-offset kt into buffer b (wave-uniform LDS dests, lane*16B implicit)
    auto stg = [&](int b, int kt) {
        short* base = &LDS[b][0];
        gld16(Ahi + aof + kt, base + wv * 512);
        gld16(Alo + aof + kt, base + 2048 + wv * 512);
        gld16(Whi + wof0 + kt, base + 4096 + wv * 512);
        gld16(Whi + wof1 + kt, base + 6144 + wv * 512);
        gld16(Wlo + wof0 + kt, base + 8192 + wv * 512);
        gld16(Wlo + wof1 + kt, base + 10240 + wv * 512);
    };

    // --- fragment read offsets (shorts), swizzled slot ---
    int sl8 = (q ^ ((ln >> 1) & 3)) * 8;
    int aoA[4], woW[2];
#pragma unroll
    for (int mf = 0; mf < 4; mf++) aoA[mf] = (mf * 16 + ln) * 32 + sl8;
#pragma unroll
    for (int nf = 0; nf < 2; nf++) woW[nf] = (wv * 32 + nf * 16 + ln) * 32 + sl8;

    f4v acc[4][2];
#pragma unroll
    for (int mf = 0; mf < 4; mf++)
#pragma unroll
        for (int nf = 0; nf < 2; nf++)
#pragma unroll
            for (int r = 0; r < 4; r++) acc[mf][nf][r] = 0.f;

    const int nt = K >> 5;
    stg(0, 0);                                  // prologue
    int cur = 0;
#pragma unroll 2
    for (int t = 0; t < nt; t++) {
        __syncthreads();                        // drains vmcnt(0): buf[cur] ready; WAR-release buf[cur^1]
        if (t + 1 < nt) stg(cur ^ 1, (t + 1) << 5);

        const short* Ah = &LDS[cur][0];
        const short* Al = Ah + 2048;
        const short* Wh = Ah + 4096;
        const short* Wl = Ah + 8192;
        s8v ah[4], al[4], bh[2], bl[2];
#pragma unroll
        for (int mf = 0; mf < 4; mf++) {
            ah[mf] = *(const s8v*)(&Ah[aoA[mf]]);
            al[mf] = *(const s8v*)(&Al[aoA[mf]]);
        }
#pragma unroll
        for (int nf = 0; nf < 2; nf++) {
            bh[nf] = *(const s8v*)(&Wh[woW[nf]]);
            bl[nf] = *(const s8v*)(&Wl[woW[nf]]);
        }
#pragma unroll
        for (int mf = 0; mf < 4; mf++)
#pragma unroll
            for (int nf = 0; nf < 2; nf++) {
                acc[mf][nf] = __builtin_amdgcn_mfma_f32_16x16x32_bf16(ah[mf], bh[nf], acc[mf][nf], 0, 0, 0);
                acc[mf][nf] = __builtin_amdgcn_mfma_f32_16x16x32_bf16(ah[mf], bl[nf], acc[mf][nf], 0, 0, 0);
                acc[mf][nf] = __builtin_amdgcn_mfma_f32_16x16x32_bf16(al[mf], bh[nf], acc[mf][nf], 0, 0, 0);
            }
        cur ^= 1;
    }

#pragma unroll
    for (int mf = 0; mf < 4; mf++) {
#pragma unroll
        for (int r = 0; r < 4; r++) {
            int row = m0 + mf * 16 + q * 4 + r;
            if (row >= M) continue;
#pragma unroll
            for (int nf = 0; nf < 2; nf++) {
                int col = n0 + nf * 16 + ln;
                if (col >= N) continue;
                float v = acc[mf][nf][r];
                v *= scale;
                if (bias) v += bias[boff + col];
                if (ACT) v = fmaxf(v, 0.f);
                if (RES) v += res[(size_t)(row >> 3) * 768 + col];
                long o = ob + (long)(row / orpb) * ostride + (long)(row % orpb) * osub
                       + coff + (long)col * cscale;
                if (OMODE == 0 || OMODE == 2) Cout[o] = v;
                if (OMODE >= 1) { short h, lo2; split1(v, h, lo2); Ohi[o] = h; Olo[o] = lo2; }
            }
        }
    }
}

// ===== direct-global fallback (used only for pre-L1 when workspace can't hold split W1) =====
template<int ACT, bool RES, int OMODE, bool WSPLIT>
__global__ __launch_bounds__(256)
void mm(const short* __restrict__ Ahi, const short* __restrict__ Alo,
        int lda, int arpb, long abst, long aoff,
        long az1b, long az1, long az2, int zdiv2, int zdiv,
        const short* __restrict__ Whi, const short* __restrict__ Wlo,
        const float* __restrict__ Wf,
        long woff, int ldw, long wz1b, long wz1, long wz2,
        const float* __restrict__ bias, long boff, float scale,
        float* __restrict__ Cout, short* __restrict__ Ohi, short* __restrict__ Olo,
        long oz1b, long oz1, long oz2,
        int orpb, long ostride, long osub, long coff, long cscale,
        const float* __restrict__ res,
        int M, int N, int K)
{
    const int tid = threadIdx.x;
    const int w = tid >> 6, l = tid & 63, q = l >> 4, ln = l & 15;
    const int n0 = blockIdx.x * 128 + w * 32;
    const int m0 = blockIdx.y * 64;
    const int z = blockIdx.z;
    int zh_all = z / zdiv, zl = z - zh_all * zdiv;
    int zt = zh_all / zdiv2, zh = zh_all - zt * zdiv2;
    long ab = (long)zt * az1b + (long)zh * az1 + (long)zl * az2;
    long wb = (long)zt * wz1b + (long)zh * wz1 + (long)zl * wz2;
    long ob = (long)zt * oz1b + (long)zh * oz1 + (long)zl * oz2;

    long aofs[4];
#pragma unroll
    for (int mf = 0; mf < 4; mf++) {
        int rm = m0 + mf * 16 + ln;
        if (rm > M - 1) rm = M - 1;
        aofs[mf] = ab + aoff + (long)(rm / arpb) * abst + (long)(rm % arpb) * lda + q * 8;
    }
    long wofs[2];
#pragma unroll
    for (int nf = 0; nf < 2; nf++)
        wofs[nf] = woff + wb + (long)(n0 + nf * 16 + ln) * ldw + q * 8;

    f4v acc[4][2];
#pragma unroll
    for (int mf = 0; mf < 4; mf++)
#pragma unroll
        for (int nf = 0; nf < 2; nf++)
#pragma unroll
            for (int r = 0; r < 4; r++) acc[mf][nf][r] = 0.f;

#pragma unroll 2
    for (int k = 0; k < K; k += 32) {
        s8v ah[4], al[4], bh[2], bl[2];
#pragma unroll
        for (int mf = 0; mf < 4; mf++) {
            ah[mf] = *(const s8v*)(const void*)(Ahi + aofs[mf] + k);
            al[mf] = *(const s8v*)(const void*)(Alo + aofs[mf] + k);
        }
#pragma unroll
        for (int nf = 0; nf < 2; nf++) {
            if (WSPLIT) {
                bh[nf] = *(const s8v*)(const void*)(Whi + wofs[nf] + k);
                bl[nf] = *(const s8v*)(const void*)(Wlo + wofs[nf] + k);
            } else {
                f8v wv = *(const f8v*)(const void*)(Wf + wofs[nf] + k);
                split8(wv, bh[nf], bl[nf]);
            }
        }
#pragma unroll
        for (int mf = 0; mf < 4; mf++)
#pragma unroll
            for (int nf = 0; nf < 2; nf++) {
                acc[mf][nf] = __builtin_amdgcn_mfma_f32_16x16x32_bf16(ah[mf], bh[nf], acc[mf][nf], 0, 0, 0);
                acc[mf][nf] = __builtin_amdgcn_mfma_f32_16x16x32_bf16(ah[mf], bl[nf], acc[mf][nf], 0, 0, 0);
                acc[mf][nf] = __builtin_amdgcn_mfma_f32_16x16x32_bf16(al[mf], bh[nf], acc[mf][nf], 0, 0, 0);
            }
    }

#pragma unroll
    for (int mf = 0; mf < 4; mf++) {
#pragma unroll
        for (int r = 0; r < 4; r++) {
            int row = m0 + mf * 16 + q * 4 + r;
            if (row >= M) continue;
#pragma unroll
            for (int nf = 0; nf < 2; nf++) {
                int col = n0 + nf * 16 + ln;
                if (col >= N) continue;
                float v = acc[mf][nf][r];
                v *= scale;
                if (bias) v += bias[boff + col];
                if (ACT) v = fmaxf(v, 0.f);
                if (RES) v += res[(size_t)(row >> 3) * 768 + col];
                long o = ob + (long)(row / orpb) * ostride + (long)(row % orpb) * osub
                       + coff + (long)col * cscale;
                if (OMODE == 0 || OMODE == 2) Cout[o] = v;
                if (OMODE >= 1) { short h, lo2; split1(v, h, lo2); Ohi[o] = h; Olo[o] = lo2; }
            }
        }
    }
}

// row-wise in-place softmax; also emits split(hi,lo); grid.x = #rows, 256 threads
__global__ void softmax_rows(float* __restrict__ sc, short* __restrict__ hi,
                             short* __restrict__ lo, int len)
{
    size_t base = (size_t)blockIdx.x * len;
    float* p = sc + base;
    __shared__ float red[256];
    int tid = threadIdx.x;
    float m = -1e30f;
    for (int i = tid; i < len; i += 256) m = fmaxf(m, p[i]);
    red[tid] = m; __syncthreads();
    for (int o = 128; o > 0; o >>= 1) {
        if (tid < o) red[tid] = fmaxf(red[tid], red[tid + o]);
        __syncthreads();
    }
    float mx = red[0]; __syncthreads();
    float s = 0.f;
    for (int i = tid; i < len; i += 256) { float e = expf(p[i] - mx); p[i] = e; s += e; }
    red[tid] = s; __syncthreads();
    for (int o = 128; o > 0; o >>= 1) {
        if (tid < o) red[tid] += red[tid + o];
        __syncthreads();
    }
    float inv = 1.f / red[0]; __syncthreads();
    for (int i = tid; i < len; i += 256) {
        float v = p[i] * inv;
        p[i] = v;
        short h, l2; split1(v, h, l2);
        hi[base + i] = h; lo[base + i] = l2;
    }
}

// wmask over chunk: block z = tch*8 + b; sc2 laid [tch][b][h][8][128]; split output
__global__ void wmask_kernel(const float* __restrict__ sc2, short* __restrict__ wh,
                             short* __restrict__ wl)
{
    int z = blockIdx.x;
    const float* src = sc2 + (size_t)z * 12288;
    for (int idx = threadIdx.x; idx < 1024; idx += 256) {
        float s = 0.f;
        for (int h = 0; h < NH_; h++) s += src[h * 1024 + idx];
        float v = s * (1.f / 12.f);
        short h2, l2; split1(v, h2, l2);
        wh[(size_t)z * 1024 + idx] = h2;
        wl[(size_t)z * 1024 + idx] = l2;
    }
}

// GRU states for all 8 candidate predecessors of every (t, b, a); split output.
// chunk rows: R = tloc*512 + b*64 + ap*8 + a
__global__ void gru_cand(const float* __restrict__ gi_all, const float* __restrict__ ghall,
                         const float* __restrict__ gh0, const float* __restrict__ pre_all,
                         const float* __restrict__ s0p,
                         short* __restrict__ sh, short* __restrict__ sl, int t0c)
{
    long idx = (long)blockIdx.x * 256 + threadIdx.x;   // exactly nt*512*768
    int c = (int)(idx % 768);
    long r = idx / 768;
    int tloc = (int)(r / 512), rem = (int)(r % 512);
    int b = rem >> 6, ap = (rem >> 3) & 7, a = rem & 7;
    int t = t0c + tloc;
    const float* gi = gi_all + ((long)t * 64 + b * 8 + a) * 2304;
    const float* gh; float hv;
    if (t == 0) { gh = gh0; hv = s0p[c]; }
    else {
        long j = (long)(t - 1) * 64 + b * 8 + ap;
        gh = ghall + j * 2304;
        hv = pre_all[j * 768 + c];
    }
    float ir  = gi[c], iz = gi[768 + c], inn = gi[1536 + c];
    float rg = 1.f / (1.f + expf(-(ir + gh[c])));
    float zg = 1.f / (1.f + expf(-(iz + gh[768 + c])));
    float ng = tanhf(inn + rg * gh[1536 + c]);
    float v = (1.f - zg) * ng + zg * hv;
    short h2, l2; split1(v, h2, l2);
    sh[idx] = h2; sl[idx] = l2;
}

// logits for candidate rows: lc[t0c*512 + blk*64 + r] = s1H_row . w2 + b2
__global__ void logits_cand_k(const float* __restrict__ s1H, const float* __restrict__ w2,
                              const float* __restrict__ b2, float* __restrict__ lc, int t0c)
{
    __shared__ float red[256];
    int blk = blockIdx.x;
    int tid = threadIdx.x, r = tid >> 2, p = tid & 3;
    const float* rp = s1H + ((size_t)blk * 64 + r) * 768 + p * 192;
    const float* wp = w2 + p * 192;
    float s = 0.f;
    for (int i = 0; i < 192; i++) s = fmaf(rp[i], wp[i], s);
    red[tid] = s; __syncthreads();
    if (p == 0)
        lc[(size_t)t0c * 512 + (size_t)blk * 64 + r]
            = red[tid] + red[tid + 1] + red[tid + 2] + red[tid + 3] + b2[0];
}

// walk the argmax chain through the precomputed candidate-logits table; 64 threads
__global__ void chain_k(const float* __restrict__ lc, float* __restrict__ out)
{
    __shared__ float lrow[64];
    __shared__ int am[8];
    int tid = threadIdx.x;            // b*8 + a
    int b = tid >> 3, a = tid & 7;
    for (int t = 0; t < T_; t++) {
        int cand = (t == 0) ? 0 : am[b];
        float v = lc[t * 512 + b * 64 + cand * 8 + a];
        out[((size_t)(b * T_ + t)) * A_ + a] = v;
        lrow[tid] = v;
        __syncthreads();
        if (a == 0) {
            float best = lrow[b * 8]; int bi = 0;
            for (int x = 1; x < 8; x++) { float w = lrow[b * 8 + x]; if (w > best) { best = w; bi = x; } }
            am[b] = bi;
        }
        __syncthreads();
    }
}

// ===== host =====
struct SB { short* h; short* l; };

template<int ACT, int OM>
static inline void MMs(hipStream_t st, SB A, int lda, int arpb, long abst, long aoff,
                       SB W, long woff, int ldw, const float* bias, long boff,
                       float* Cf, SB O, long ldc, long coff, int M, int N, int K)
{
    dim3 g((unsigned)((N + 127) / 128), (unsigned)((M + 63) / 64), 1), b(256);
    mml<ACT, false, OM><<<g, b, 0, st>>>(A.h, A.l, lda, arpb, abst, aoff,
        0, 0, 0, NP, 1, W.h, W.l, woff, ldw, 0, 0, 0,
        bias, boff, 1.f, Cf, O.h, O.l, 0, 0, 0, 1, ldc, 0, coff, 1, nullptr, M, N, K);
}

extern "C" void kernel_launch(void* const* d_in, const int* in_sizes, int n_in,
                              void* d_out, int out_size, void* d_ws, size_t ws_size,
                              hipStream_t stream)
{
    const float* video     = (const float*)d_in[0];
    const float* script    = (const float*)d_in[1];
    const float* question  = (const float*)d_in[2];
    const float* a_texts   = (const float*)d_in[3];
    const float* a_buttons = (const float*)d_in[4];
    const float* state0    = (const float*)d_in[5];
    const float* mlp_v_w1 = (const float*)d_in[6];  const float* mlp_v_b1 = (const float*)d_in[7];
    const float* mlp_v_w2 = (const float*)d_in[8];  const float* mlp_v_b2 = (const float*)d_in[9];
    const float* mlp_t_w1 = (const float*)d_in[10]; const float* mlp_t_b1 = (const float*)d_in[11];
    const float* mlp_t_w2 = (const float*)d_in[12]; const float* mlp_t_b2 = (const float*)d_in[13];
    const float* pre_w1   = (const float*)d_in[14]; const float* pre_b1   = (const float*)d_in[15];
    const float* pre_w2   = (const float*)d_in[16]; const float* pre_b2   = (const float*)d_in[17];
    const float* s2v_in_w = (const float*)d_in[18]; const float* s2v_in_b = (const float*)d_in[19];
    const float* s2v_out_w= (const float*)d_in[20]; const float* s2v_out_b= (const float*)d_in[21];
    const float* qa2s_in_w= (const float*)d_in[22]; const float* qa2s_in_b= (const float*)d_in[23];
    const float* qa2s_out_w=(const float*)d_in[24]; const float* qa2s_out_b=(const float*)d_in[25];
    const float* gru_w_ih = (const float*)d_in[26]; const float* gru_w_hh = (const float*)d_in[27];
    const float* gru_b_ih = (const float*)d_in[28]; const float* gru_b_hh = (const float*)d_in[29];
    const float* proj_w1  = (const float*)d_in[30]; const float* proj_b1  = (const float*)d_in[31];
    const float* proj_w2  = (const float*)d_in[32]; const float* proj_b2  = (const float*)d_in[33];
    float* out = (float*)d_out;
    (void)in_sizes; (void)n_in; (void)out_size;

    hipStream_t st = stream;
    dim3 blk(256);
    const long DDL = 589824;

    // ---- workspace bump allocator (units of 4 bytes) ----
    float* fb = (float*)d_ws;
    auto take = [&](long n) { float* p = fb; fb += n; return p; };
    auto mksb = [&](long n) { float* p = take(n); SB s; s.h = (short*)p; s.l = s.h + n; return s; };

    // split weights (persistent)
    SB w_v1 = mksb(589824),  w_v2 = mksb(589824);
    SB w_t1 = mksb(589824),  w_t2 = mksb(589824);
    SB s2vi = mksb(1769472), s2vo = mksb(589824);
    SB qa2i = mksb(1769472), qa2o = mksb(589824);
    SB gih  = mksb(1769472), ghh  = mksb(1769472);
    SB pj1  = mksb(589824),  pw2  = mksb(4718592);
    // split inputs
    SB sVid = mksb(3145728), sScr = mksb(786432), sQue = mksb(6144);
    SB sAtx = mksb(786432),  sAbt = mksb(3932160), sS0 = mksb(768);
    // persistent activations
    SB svat = mksb(786432), sk2 = mksb(786432), sv2T = mksb(786432);
    float* q_t     = take(6144);
    float* gh0     = take(2304);
    float* pre_all = take(786432);
    SB spre        = mksb(786432);
    float* lc      = take(8192);

    long wsF = (long)(ws_size / 4);
    long dynMin = 5505024;
    bool w1split = ((fb - (float*)d_ws) + 37748736L + dynMin + 64) <= wsF;
    SB pw1s = { nullptr, nullptr };
    if (w1split) pw1s = mksb(37748736);

    float* U = fb;
    long dynF = wsF - (fb - (float*)d_ws) - 64;

    int g = 1;
    for (int c = 8; c >= 1; c >>= 1) { if (1572864L + (long)c * 2752512L <= dynF) { g = c; break; } }
    int TG = 1;
    for (int c = 16; c >= 1; c >>= 1) { if ((long)c * 1384448L <= dynF) { TG = c; break; } }
    int TG2 = 1;
    for (int c = 16; c >= 1; c >>= 1) { if (4718592L + (long)c * 786432L <= dynF) { TG2 = c; break; } }

    // ---- conversions ----
    auto SPL = [&](const float* x, SB s, long n) {
        long n8 = n / 8;
        split_arr<<<dim3((unsigned)((n8 + 255) / 256)), blk, 0, st>>>(x, s.h, s.l, n8);
    };
    SPL(mlp_v_w1, w_v1, 589824);  SPL(mlp_v_w2, w_v2, 589824);
    SPL(mlp_t_w1, w_t1, 589824);  SPL(mlp_t_w2, w_t2, 589824);
    SPL(s2v_in_w, s2vi, 1769472); SPL(s2v_out_w, s2vo, 589824);
    SPL(qa2s_in_w, qa2i, 1769472);SPL(qa2s_out_w, qa2o, 589824);
    SPL(gru_w_ih, gih, 1769472);  SPL(gru_w_hh, ghh, 1769472);
    SPL(proj_w1, pj1, 589824);    SPL(pre_w2, pw2, 4718592);
    SPL(video, sVid, 3145728);    SPL(script, sScr, 786432);
    SPL(question, sQue, 6144);    SPL(a_texts, sAtx, 786432);
    SPL(a_buttons, sAbt, 3932160);SPL(state0, sS0, 768);
    if (w1split) SPL(pre_w1, pw1s, 37748736);

    // ======== phase 1 ========
    // phase-1 view of U
    SB sqp   = { (short*)U, (short*)U + 786432 };
    SB satt  = { (short*)(U + 786432), (short*)(U + 786432) + 786432 };
    float* G0 = U + 1572864;
    SB sbufA = { (short*)G0, (short*)G0 + (long)g * 393216 };
    SB sbufB = { (short*)(G0 + (long)g * 393216), (short*)(G0 + (long)g * 393216) + (long)g * 393216 };
    SB sbufD = { (short*)(G0 + 2L * g * 393216), (short*)(G0 + 2L * g * 393216) + (long)g * 393216 };
    float* sc_g = G0 + 3L * g * 393216;
    SB ssc_g = { (short*)(sc_g + (long)g * 786432), (short*)(sc_g + (long)g * 786432) + (long)g * 786432 };
    SB sscrH = { (short*)G0, (short*)G0 + 786432 };
    SB sscrT = { (short*)(G0 + 786432), (short*)(G0 + 786432) + 786432 };
    SB sqH   = { (short*)(G0 + 1572864), (short*)(G0 + 1572864) + 6144 };

    MMs<0, 1>(st, sScr, D_, NP, 0, 0, s2vi, 0, D_, s2v_in_b, 0, nullptr, sqp, D_, 0, 1024, D_, D_);
    for (int s0 = 0; s0 < B_; s0 += g) {
        int Mg = 512 * g;
        long voff = (long)s0 * 393216;
        MMs<1, 1>(st, sVid, D_, NP, 0, voff, w_v1, 0, D_, mlp_v_b1, 0, nullptr, sbufA, D_, 0, Mg, D_, D_);
        MMs<0, 1>(st, sbufA, D_, NP, 0, 0, w_v2, 0, D_, mlp_v_b2, 0, nullptr, sbufB, D_, 0, Mg, D_, D_);
        MMs<0, 1>(st, sbufB, D_, NP, 0, 0, s2vi, DDL, D_, s2v_in_b, D_, nullptr, sbufA, D_, 0, Mg, D_, D_); // kp
        {   // vpT: out o = (row/512)*393216 + row%512 + col*512
            dim3 gr(6, (unsigned)(Mg / 64), 1);
            mml<0, false, 1><<<gr, blk, 0, st>>>(sbufB.h, sbufB.l, D_, NP, 0, 0, 0, 0, 0, NP, 1,
                s2vi.h, s2vi.l, 2 * DDL, D_, 0, 0, 0, s2v_in_b, 2 * D_, 1.f,
                nullptr, sbufD.h, sbufD.l, 0, 0, 0, 512, 393216, 1, 0, 512, nullptr, Mg, D_, D_);
        }
        {   // scores (fp32): sc_g[z=lb*12+h][i][j] = 0.125 * qp_i . kp_j (dh slice h)
            dim3 gr(4, 2, (unsigned)(12 * g));
            mml<0, false, 0><<<gr, blk, 0, st>>>(sqp.h, sqp.l, D_, NP, 0, (long)s0 * 98304,
                0, 98304, 64, NP, 12,
                sbufA.h, sbufA.l, 0, D_, 0, 393216, 64, nullptr, 0, 0.125f,
                sc_g, nullptr, nullptr, 0, 786432, 65536, 1, 512, 0, 0, 1, nullptr, S_, V_, 64);
        }
        softmax_rows<<<dim3((unsigned)(12 * g * 128)), blk, 0, st>>>(sc_g, ssc_g.h, ssc_g.l, 512);
        {   // PV: attnout[b*128+i][h*64+d] = P . V
            dim3 gr(1, 2, (unsigned)(12 * g));
            mml<0, false, 1><<<gr, blk, 0, st>>>(ssc_g.h, ssc_g.l, 512, NP, 0, 0,
                0, 786432, 65536, NP, 12,
                sbufD.h, sbufD.l, 0, 512, 0, 393216, 32768, nullptr, 0, 1.f,
                nullptr, satt.h, satt.l, 0, 98304, 64, 1, 768, 0, (long)s0 * 98304, 1, nullptr, S_, 64, 512);
        }
    }
    {   // vid_attT: out o = (row/128)*98304 + row%128 + col*128
        dim3 gr(6, 16, 1);
        mml<0, false, 1><<<gr, blk, 0, st>>>(satt.h, satt.l, D_, NP, 0, 0, 0, 0, 0, NP, 1,
            s2vo.h, s2vo.l, 0, D_, 0, 0, 0, s2v_out_b, 0, 1.f,
            nullptr, svat.h, svat.l, 0, 0, 0, 128, 98304, 1, 0, 128, nullptr, 1024, D_, D_);
    }
    MMs<1, 1>(st, sScr, D_, NP, 0, 0, w_t1, 0, D_, mlp_t_b1, 0, nullptr, sscrH, D_, 0, 1024, D_, D_);
    MMs<0, 1>(st, sscrH, D_, NP, 0, 0, w_t2, 0, D_, mlp_t_b2, 0, nullptr, sscrT, D_, 0, 1024, D_, D_);
    MMs<0, 1>(st, sscrT, D_, NP, 0, 0, qa2i, DDL, D_, qa2s_in_b, D_, nullptr, sk2, D_, 0, 1024, D_, D_);
    {   // v2T: out o = (row/128)*98304 + row%128 + col*128
        dim3 gr(6, 16, 1);
        mml<0, false, 1><<<gr, blk, 0, st>>>(sscrT.h, sscrT.l, D_, NP, 0, 0, 0, 0, 0, NP, 1,
            qa2i.h, qa2i.l, 2 * DDL, D_, 0, 0, 0, qa2s_in_b, 2 * D_, 1.f,
            nullptr, sv2T.h, sv2T.l, 0, 0, 0, 128, 98304, 1, 0, 128, nullptr, 1024, D_, D_);
    }
    MMs<1, 1>(st, sQue, D_, NP, 0, 0, w_t1, 0, D_, mlp_t_b1, 0, nullptr, sqH, D_, 0, B_, D_, D_);
    MMs<0, 0>(st, sqH, D_, NP, 0, 0, w_t2, 0, D_, mlp_t_b2, 0, q_t, SB{nullptr, nullptr}, D_, 0, B_, D_, D_);

    // ======== batched scan precompute (chunks of TG timesteps) ========
    for (int t0 = 0; t0 < T_; t0 += TG) {
        float* p = U;
        SB sinp  = { (short*)p, (short*)p + (long)TG * 393216 }; p += (long)TG * 393216;
        SB spreH = { (short*)p, (short*)p + (long)TG * 393216 }; p += (long)TG * 393216;
        SB satH  = { (short*)p, (short*)p + (long)TG * 49152 };  p += (long)TG * 49152;
        SB sabH  = { (short*)p, (short*)p + (long)TG * 245760 }; p += (long)TG * 245760;
        SB sqp2  = { (short*)p, (short*)p + (long)TG * 49152 };  p += (long)TG * 49152;
        float* sc2 = p;                                          p += (long)TG * 98304;
        SB ssc2  = { (short*)p, (short*)p + (long)TG * 98304 };  p += (long)TG * 98304;
        SB swm   = { (short*)p, (short*)p + (long)TG * 8192 };   p += (long)TG * 8192;
        SB satt2 = { (short*)p, (short*)p + (long)TG * 49152 };  p += (long)TG * 49152;

        // a_t layer1 (gather over t), z = tch
        mml<1, false, 1><<<dim3(6, 1, TG), blk, 0, st>>>(sAtx.h, sAtx.l, D_, A_, 98304,
            (long)t0 * 6144, 0, 6144, 0, NP, 1,
            w_t1.h, w_t1.l, 0, D_, 0, 0, 0, mlp_t_b1, 0, 1.f,
            nullptr, satH.h, satH.l, 0, 49152, 0, 1, 768, 0, 0, 1, nullptr, 64, D_, D_);
        // a_t layer2 + q_t -> inputs[:,1536:2304]
        mml<0, true, 1><<<dim3(6, 1, TG), blk, 0, st>>>(satH.h, satH.l, D_, NP, 0, 0,
            0, 49152, 0, NP, 1,
            w_t2.h, w_t2.l, 0, D_, 0, 0, 0, mlp_t_b2, 0, 1.f,
            nullptr, sinp.h, sinp.l, 0, 393216, 0, 1, DIN_, 0, 1536, 1, q_t, 64, D_, D_);
        // a_b layer1 (gather over t)
        mml<1, false, 1><<<dim3(6, 5, TG), blk, 0, st>>>(sAbt.h, sAbt.l, D_, A_ * M_, 491520,
            (long)t0 * 30720, 0, 30720, 0, NP, 1,
            w_v1.h, w_v1.l, 0, D_, 0, 0, 0, mlp_v_b1, 0, 1.f,
            nullptr, sabH.h, sabH.l, 0, 245760, 0, 1, 768, 0, 0, 1, nullptr, 320, D_, D_);
        // a_b layer2 -> inputs[:,2304:6144]
        mml<0, false, 1><<<dim3(6, 5, TG), blk, 0, st>>>(sabH.h, sabH.l, D_, NP, 0, 0,
            0, 245760, 0, NP, 1,
            w_v2.h, w_v2.l, 0, D_, 0, 0, 0, mlp_v_b2, 0, 1.f,
            nullptr, sinp.h, sinp.l, 0, 393216, 0, M_, DIN_, 768, 2304, 1, nullptr, 320, D_, D_);
        // qp2 = qa @ qa2s_wq
        mml<0, false, 1><<<dim3(6, 1, TG), blk, 0, st>>>(sinp.h, sinp.l, DIN_, NP, 0, 1536,
            0, 393216, 0, NP, 1,
            qa2i.h, qa2i.l, 0, D_, 0, 0, 0, qa2s_in_b, 0, 1.f,
            nullptr, sqp2.h, sqp2.l, 0, 49152, 0, 1, 768, 0, 0, 1, nullptr, 64, D_, D_);
        // scores2 (fp32): z = tch*96 + b*12 + h
        mml<0, false, 0><<<dim3(1, 1, 96 * TG), blk, 0, st>>>(sqp2.h, sqp2.l, D_, NP, 0, 0,
            49152, 6144, 64, 8, 12,
            sk2.h, sk2.l, 0, D_, 0, 98304, 64, nullptr, 0, 0.125f,
            sc2, nullptr, nullptr, 98304, 12288, 1024, 1, 128, 0, 0, 1, nullptr, A_, S_, 64);
        softmax_rows<<<dim3((unsigned)(768 * TG)), blk, 0, st>>>(sc2, ssc2.h, ssc2.l, 128);
        wmask_kernel<<<dim3((unsigned)(8 * TG)), blk, 0, st>>>(sc2, swm.h, swm.l);
        // qa_vid = wmask @ vid_att -> inputs[:,0:768]; z = tch*8 + b
        mml<0, false, 1><<<dim3(6, 1, 8 * TG), blk, 0, st>>>(swm.h, swm.l, S_, NP, 0, 0,
            0, 8192, 1024, NP, 8,
            svat.h, svat.l, 0, 128, 0, 0, 98304, nullptr, 0, 1.f,
            nullptr, sinp.h, sinp.l, 0, 393216, 49152, 1, DIN_, 0, 0, 1, nullptr, A_, D_, S_);
        // PV2 -> att2; z = tch*96 + b*12 + h
        mml<0, false, 1><<<dim3(1, 1, 96 * TG), blk, 0, st>>>(ssc2.h, ssc2.l, S_, NP, 0, 0,
            98304, 12288, 1024, 8, 12,
            sv2T.h, sv2T.l, 0, 128, 0, 98304, 8192, nullptr, 0, 1.f,
            nullptr, satt2.h, satt2.l, 49152, 6144, 64, 1, 768, 0, 0, 1, nullptr, A_, 64, S_);
        // attn out-proj -> inputs[:,768:1536]
        mml<0, false, 1><<<dim3(6, 1, TG), blk, 0, st>>>(satt2.h, satt2.l, D_, NP, 0, 0,
            0, 49152, 0, NP, 1,
            qa2o.h, qa2o.l, 0, D_, 0, 0, 0, qa2s_out_b, 0, 1.f,
            nullptr, sinp.h, sinp.l, 0, 393216, 0, 1, DIN_, 0, 768, 1, nullptr, 64, D_, D_);
        // pre-MLP L1 (the big batched GEMM): M = TG*64
        if (w1split)
            mml<1, false, 1><<<dim3(48, TG, 1), blk, 0, st>>>(sinp.h, sinp.l, DIN_, NP, 0, 0,
                0, 0, 0, NP, 1,
                pw1s.h, pw1s.l, 0, DIN_, 0, 0, 0, pre_b1, 0, 1.f,
                nullptr, spreH.h, spreH.l, 0, 0, 0, 1, DIN_, 0, 0, 1, nullptr, TG * 64, DIN_, DIN_);
        else
            mm<1, false, 1, false><<<dim3(48, TG, 1), blk, 0, st>>>(sinp.h, sinp.l, DIN_, NP, 0, 0,
                0, 0, 0, NP, 1,
                nullptr, nullptr, pre_w1, 0, DIN_, 0, 0, 0, pre_b1, 0, 1.f,
                nullptr, spreH.h, spreH.l, 0, 0, 0, 1, DIN_, 0, 0, 1, nullptr, TG * 64, DIN_, DIN_);
        // pre-MLP L2 -> pre_all (fp32 + split)
        mml<0, false, 2><<<dim3(6, TG, 1), blk, 0, st>>>(spreH.h, spreH.l, DIN_, NP, 0, 0,
            0, 0, 0, NP, 1,
            pw2.h, pw2.l, 0, DIN_, 0, 0, 0, pre_b2, 0, 1.f,
            pre_all, spre.h, spre.l, 0, 0, 0, 1, 768, 0, (long)t0 * 49152, 1, nullptr, TG * 64, DS_, DIN_);
    }

    // ======== GRU candidate precompute ========
    float* gi_all = U;
    float* ghall  = U + 2359296;
    float* candU  = U + 4718592;
    MMs<0, 0>(st, spre, DS_, NP, 0, 0, gih, 0, DS_, gru_b_ih, 0, gi_all, SB{nullptr, nullptr}, 3 * DS_, 0, 1024, 3 * DS_, DS_);
    MMs<0, 0>(st, spre, DS_, NP, 0, 0, ghh, 0, DS_, gru_b_hh, 0, ghall, SB{nullptr, nullptr}, 3 * DS_, 0, 1024, 3 * DS_, DS_);
    MMs<0, 0>(st, sS0, DS_, NP, 0, 0, ghh, 0, DS_, gru_b_hh, 0, gh0, SB{nullptr, nullptr}, 3 * DS_, 0, 1, 3 * DS_, DS_);

    for (int t0 = 0; t0 < T_; t0 += TG2) {
        float* p = candU;
        SB sstc = { (short*)p, (short*)p + (long)TG2 * 393216 };
        float* s1H = p + (long)TG2 * 393216;
        gru_cand<<<dim3((unsigned)(TG2 * 1536)), blk, 0, st>>>(gi_all, ghall, gh0, pre_all,
                                                               state0, sstc.h, sstc.l, t0);
        MMs<1, 0>(st, sstc, DS_, NP, 0, 0, pj1, 0, DS_, proj_b1, 0, s1H, SB{nullptr, nullptr}, DS_, 0, TG2 * 512, DS_, DS_);
        logits_cand_k<<<dim3((unsigned)(TG2 * 8)), blk, 0, st>>>(s1H, proj_w2, proj_b2, lc, t0);
    }

    // ======== sequential argmax chain (trivial) ========
    chain_k<<<1, 64, 0, st>>>(lc, out);
}